// Round 11
// baseline (1911.428 us; speedup 1.0000x reference)
//
#include <hip/hip_runtime.h>
#include <hip/hip_bf16.h>

typedef unsigned short u16;
using bf16x8 = __attribute__((ext_vector_type(8))) short;
using f32x4  = __attribute__((ext_vector_type(4))) float;

#define NB   4
#define NT   90
#define NIMG 360
#define LL   240
#define DD   64
#define HID  512
#define NJ   2048
#define GPB  16            // gates blocks per batch
#define TBLK (NB * GPB)    // 64 blocks total (no attn blocks)

#define DEV __device__ __forceinline__

DEV float bf2f(u16 x){ unsigned int u = ((unsigned int)x) << 16; float f; __builtin_memcpy(&f, &u, 4); return f; }
DEV u16 f2bf(float f){ unsigned int u; __builtin_memcpy(&u, &f, 4); unsigned int r = (u + 0x7FFFu + ((u >> 16) & 1u)) >> 16; return (u16)r; }
DEV float sigm(float x){ return 1.f / (1.f + __expf(-x)); }
DEV float tanh_f(float x){ x = fminf(fmaxf(x, -15.f), 15.f); float e = __expf(2.f*x); return (e - 1.f) / (e + 1.f); }

// L3-coherent (agent-scope, relaxed) accessors for cross-XCD mutable state.
DEV void  ast(float* p, float v){ __hip_atomic_store(p, v, __ATOMIC_RELAXED, __HIP_MEMORY_SCOPE_AGENT); }
DEV float ald(const float* p){ return __hip_atomic_load(p, __ATOMIC_RELAXED, __HIP_MEMORY_SCOPE_AGENT); }
DEV unsigned int aldu(const unsigned int* p){ return __hip_atomic_load(p, __ATOMIC_RELAXED, __HIP_MEMORY_SCOPE_AGENT); }

// ---------------- workspace layout (bytes) ----------------
// G2 layout: [b][g(16)][t(90)][l(240)][128 jj] u16 — block (b,g) slice at step t is one
// contiguous 61,440B run.
static const size_t G_OFF     = 0;            // 353,894,400 B
static const size_t CAMCL_OFF = 0;            // conv temporaries alias over G
static const size_t A1_OFF    = 88473600;
static const size_t A2_OFF    = 154828800;
static const size_t A3_OFF    = 182476800;
static const size_t A4_OFF    = 190771200;
static const size_t A5_OFF    = 201830400;
static const size_t W1B_OFF   = 212889600;
static const size_t W2B_OFF   = 212903936;
static const size_t W3B_OFF   = 212968448;
static const size_t W4B_OFF   = 213075968;
static const size_t W5B_OFF   = 213137408;
static const size_t FEATS_OFF = 353894400;    // fp32 [360][240][64]; dead during scan
static const size_t SC_HX     = 353898496;    // fp32 [2][4][512] = 16KB (parity double-buffer)
static const size_t SC_CTR    = 353914880;    // u32 [4][32] = 512B (per-batch arrival counters)
static const size_t PROJ_OFF  = 376012800;    // fp32 [360][240][64]
static const size_t WWT_OFF   = 398131200;    // fp32 [512][64]   w_w^T
static const size_t WHHP_OFF  = 398262272;    // bf16 [512][2048] whh^T, j-permuted
static const size_t BSUM_OFF  = 400359424;    // fp32 [2048] bih+bhh, j-permuted
static const size_t SW1T_OFF  = 400367616;    // fp32 [512][100]
static const size_t VW1T_OFF  = 400572416;    // fp32 [512][100]
static const size_t HSEQ_OFF  = 400809984;    // fp32 [90][4][512]
static const size_t WS_NEEDED = 401547264;

// ---------------- camera NCHW fp32 -> channels-last bf16 [n][h][w][8] ----------------
__global__ __launch_bounds__(256) void cam_to_cl(const float* __restrict__ cam, u16* __restrict__ out)
{
    int i = blockIdx.x * 256 + threadIdx.x;
    if (i >= NIMG * 96 * 160) return;
    int hw = i % (96 * 160);
    int n  = i / (96 * 160);
    const float* p = cam + (size_t)n * 3 * 96 * 160 + hw;
    bf16x8 v;
    v[0] = (short)f2bf(p[0]);
    v[1] = (short)f2bf(p[15360]);
    v[2] = (short)f2bf(p[30720]);
    v[3] = 0; v[4] = 0; v[5] = 0; v[6] = 0; v[7] = 0;
    *(bf16x8*)&out[(size_t)i * 8] = v;
}

// ---------------- weight prep for convs ----------------
__global__ __launch_bounds__(256) void prep_wbf(
    const float* __restrict__ w, u16* __restrict__ wbf,
    int COUT, int CIN, int CI_PAD, int KHW, int CELLS_PAD, int M_PAD)
{
    int K_PAD = CELLS_PAD * CI_PAD;
    int total = M_PAD * K_PAD;
    for (int i = blockIdx.x * 256 + threadIdx.x; i < total; i += gridDim.x * 256){
        int co = i / K_PAD, kk = i % K_PAD;
        int cell = kk / CI_PAD, ci = kk % CI_PAD;
        float v = 0.f;
        if (co < COUT && cell < KHW * KHW && ci < CIN){
            int kh = cell / KHW, kw = cell % KHW;
            v = w[((size_t)(co * CIN + ci) * KHW + kh) * KHW + kw];
        }
        wbf[i] = f2bf(v);
    }
}

// ---------------- implicit-GEMM MFMA conv (channels-last bf16 in/out) ----------------
template<int CI_PAD, int M_PAD, int COUT, int CO_STORE, int KHW, int CELLS_PAD,
         int S, int P, int HIN, int WIN, int HOUT, int WOUT, int TOH, int TOW>
__global__ __launch_bounds__(256) void conv_mfma(
    const u16* __restrict__ in, const u16* __restrict__ wbf,
    const float* __restrict__ bias, u16* __restrict__ out)
{
    constexpr int K_PAD = CELLS_PAD * CI_PAD;
    constexpr int CP8   = CI_PAD / 8;
    constexpr int TIH   = (TOH - 1) * S + KHW;
    constexpr int TIW   = (TOW - 1) * S + KHW;
    constexpr int TIW_H = (TIW + 1) / 2;
    constexpr int NF    = TOH * TOW / 16;
    constexpr int NK0   = K_PAD / 32;
    constexpr int MF    = M_PAD / 16;
    constexpr int NPW   = (NF + 3) / 4;
    constexpr int LDSE  = (S == 2) ? TIH * CP8 * 2 * TIW_H * 8 : TIH * CP8 * TIW * 8;
    static_assert((TOH * TOW) % 16 == 0, "N tile");
    static_assert(K_PAD % 32 == 0, "K pad");

    __shared__ u16 lds[LDSE];

    int tile = blockIdx.x, n = blockIdx.y;
    constexpr int TW_T = WOUT / TOW;
    int th = tile / TW_T, tw = tile % TW_T;
    int oh0 = th * TOH, ow0 = tw * TOW;
    int ih0 = oh0 * S - P, iw0 = ow0 * S - P;
    int tid = threadIdx.x;

    constexpr int CHUNKS = TIH * TIW * CP8;
    for (int i = tid; i < CHUNKS; i += 256){
        int c8 = i % CP8; int r2 = i / CP8;
        int iw = r2 % TIW, ih = r2 / TIW;
        int ihg = ih0 + ih, iwg = iw0 + iw;
        bf16x8 v = {0,0,0,0,0,0,0,0};
        if (ihg >= 0 && ihg < HIN && iwg >= 0 && iwg < WIN)
            v = *(const bf16x8*)&in[(((size_t)n * HIN + ihg) * WIN + iwg) * CI_PAD + c8 * 8];
        int off;
        if (S == 2) off = (((ih * CP8 + c8) * 2 + (iw & 1)) * TIW_H + (iw >> 1)) * 8;
        else        off = ((ih * CP8 + c8) * TIW + iw) * 8;
        *(bf16x8*)&lds[off] = v;
    }
    __syncthreads();

    int lane = tid & 63, wv = tid >> 6;
    int col = lane & 15, grp = lane >> 4;

    int ihb[NPW], iwb[NPW];
    bool act[NPW];
#pragma unroll
    for (int i2 = 0; i2 < NPW; i2++){
        int nf = wv + i2 * 4;
        act[i2] = (nf < NF);
        int nfc = act[i2] ? nf : 0;
        int nsp = nfc * 16 + col;
        ihb[i2] = (nsp / TOW) * S;
        iwb[i2] = (nsp % TOW) * S;
    }

    f32x4 acc[MF][NPW];
#pragma unroll
    for (int mf = 0; mf < MF; mf++)
#pragma unroll
        for (int i2 = 0; i2 < NPW; i2++)
            acc[mf][i2] = (f32x4){0.f, 0.f, 0.f, 0.f};

    for (int k0 = 0; k0 < NK0; k0++){
        bf16x8 a[MF];
#pragma unroll
        for (int mf = 0; mf < MF; mf++)
            a[mf] = *(const bf16x8*)&wbf[(size_t)(mf * 16 + col) * K_PAD + k0 * 32 + grp * 8];
        int k8 = k0 * 32 + grp * 8;
        int cell = k8 / CI_PAD;
        int ci0  = k8 - cell * CI_PAD;
        if (cell >= KHW * KHW) cell = 0;
        int kh = cell / KHW, kw = cell - (cell / KHW) * KHW;
        int cb = ci0 >> 3;
#pragma unroll
        for (int i2 = 0; i2 < NPW; i2++){
            if (!act[i2]) continue;
            int ih = ihb[i2] + kh;
            int off;
            if (S == 2) off = (((ih * CP8 + cb) * 2 + (kw & 1)) * TIW_H + (iwb[i2] >> 1) + (kw >> 1)) * 8;
            else        off = ((ih * CP8 + cb) * TIW + iwb[i2] + kw) * 8;
            bf16x8 b = *(const bf16x8*)&lds[off];
#pragma unroll
            for (int mf = 0; mf < MF; mf++)
                acc[mf][i2] = __builtin_amdgcn_mfma_f32_16x16x32_bf16(a[mf], b, acc[mf][i2], 0, 0, 0);
        }
    }

#pragma unroll
    for (int i2 = 0; i2 < NPW; i2++){
        if (!act[i2]) continue;
        int nf = wv + i2 * 4;
        int nsp = nf * 16 + col;
        int oh = oh0 + nsp / TOW, ow = ow0 + nsp % TOW;
        size_t obase = (((size_t)n * HOUT + oh) * WOUT + ow) * CO_STORE;
#pragma unroll
        for (int mf = 0; mf < MF; mf++){
            int cobase = mf * 16 + grp * 4;
#pragma unroll
            for (int r = 0; r < 4; r++){
                int co = cobase + r;
                if (co < CO_STORE){
                    float x = (co < COUT) ? fmaxf(acc[mf][i2][r] + bias[co], 0.f) : 0.f;
                    out[obase + co] = f2bf(x);
                }
            }
        }
    }
}

// ---------------- feats rearrange ----------------
__global__ __launch_bounds__(256) void extract_feats(const u16* __restrict__ a5, float* __restrict__ feats)
{
    int idx = blockIdx.x * 256 + threadIdx.x;
    if (idx >= NIMG * 12 * 20 * 64) return;
    int c = idx & 63; int t1 = idx >> 6;
    int w = t1 % 20; t1 /= 20;
    int h = t1 % 12; int n = t1 / 12;
    float v = bf2f(a5[idx]);
    int flat = w * 768 + c * 12 + h;
    int d = flat / 240, l = flat % 240;
    feats[((size_t)n * LL + l) * DD + d] = v;
}

// ---------------- proj = feats @ proj_w.T + proj_b ----------------
__global__ __launch_bounds__(256) void proj_kernel(
    const float* __restrict__ feats, const float* __restrict__ pw,
    const float* __restrict__ pb, float* __restrict__ proj)
{
    __shared__ float pws[64][65];
    __shared__ float fs[4][64];
    int tid = threadIdx.x;
    size_t R0 = (size_t)blockIdx.x * 4;
    for (int i = tid; i < 4096; i += 256){
        int dd = i / 64, d = i % 64;
        pws[d][dd] = pw[dd*64 + d];
    }
    { int r = tid / 64, d = tid % 64; fs[r][d] = feats[(R0 + r)*64 + d]; }
    __syncthreads();
    int r = tid / 64, dd = tid % 64;
    float a = pb[dd];
    for (int d = 0; d < 64; d++) a = fmaf(fs[r][d], pws[d][dd], a);
    proj[(R0 + r)*64 + dd] = a;
}

// ---------------- prep: whh permute, bias combine, w_w transpose ----------------
__global__ __launch_bounds__(256) void prep(
    const float* __restrict__ w_w, const float* __restrict__ whh,
    const float* __restrict__ bih, const float* __restrict__ bhh,
    float* __restrict__ w_wT, u16* __restrict__ whh_p, float* __restrict__ bsum)
{
    int idx = blockIdx.x * 256 + threadIdx.x;
    int stride = gridDim.x * 256;
    for (int i = idx; i < 512*64; i += stride){
        int k = i / 64, dd = i % 64;
        w_wT[i] = w_w[dd*512 + k];
    }
    for (int i = idx; i < 512*2048; i += stride){
        int k = i / 2048, jj = i % 2048;
        int u = jj >> 2, g = jj & 3, j = g*512 + u;
        whh_p[i] = f2bf(whh[(size_t)j*512 + k]);
    }
    for (int i = idx; i < 2048; i += stride){
        int u = i >> 2, g = i & 3, j = g*512 + u;
        bsum[i] = bih[j] + bhh[j];
    }
}

// ---------------- prep2: MLP first-layer transposes ----------------
__global__ __launch_bounds__(256) void prep2(
    const float* __restrict__ sw1, const float* __restrict__ vw1,
    float* __restrict__ sw1T, float* __restrict__ vw1T)
{
    int idx = blockIdx.x * 256 + threadIdx.x;
    int stride = gridDim.x * 256;
    for (int i = idx; i < 512*100; i += stride){
        int k = i / 100, u = i % 100;
        sw1T[i] = sw1[u*512 + k];
        vw1T[i] = vw1[u*512 + k];
    }
}

// ---------------- gcompute via MFMA; G2 slice-contiguous layout ----------------
__global__ __launch_bounds__(256, 2) void gcompute_mfma2(
    const float* __restrict__ feats, const float* __restrict__ wih, u16* __restrict__ G)
{
    __shared__ u16 Bsw[256 * 64];
    __shared__ u16 Asw[128 * 64];
    float (*obuf)[1024] = (float(*)[1024])Asw;

    int jt = blockIdx.x, l = blockIdx.y;
    int j0 = jt * 256;
    int tid = threadIdx.x;
    int g8 = tid & 7;

    for (int p = 0; p < 8; p++){
        int row = p * 32 + (tid >> 3);
        int jj = j0 + row;
        int j = (jj & 3) * 512 + (jj >> 2);
        const float* src = wih + (size_t)j * 15360 + l * 64 + g8 * 8;
        float4 v0 = *(const float4*)src;
        float4 v1 = *(const float4*)(src + 4);
        bf16x8 pk;
        pk[0]=(short)f2bf(v0.x); pk[1]=(short)f2bf(v0.y); pk[2]=(short)f2bf(v0.z); pk[3]=(short)f2bf(v0.w);
        pk[4]=(short)f2bf(v1.x); pk[5]=(short)f2bf(v1.y); pk[6]=(short)f2bf(v1.z); pk[7]=(short)f2bf(v1.w);
        *(bf16x8*)&Bsw[(row * 8 + (g8 ^ (row & 7))) * 8] = pk;
    }
    __syncthreads();

    int lane = tid & 63, w = tid >> 6;
    int col = lane & 15, grp = lane >> 4;

    bf16x8 bfr[2][4];
#pragma unroll
    for (int k0 = 0; k0 < 2; k0++)
#pragma unroll
        for (int nf = 0; nf < 4; nf++){
            int row = w * 64 + nf * 16 + col;
            bfr[k0][nf] = *(const bf16x8*)&Bsw[(row * 8 + ((k0 * 4 + grp) ^ (row & 7))) * 8];
        }

    for (int mt = 0; mt < 3; mt++){
        int m0 = mt * 128;
        __syncthreads();
        for (int p = 0; p < 4; p++){
            int row = p * 32 + (tid >> 3);
            const float* src = feats + ((size_t)(m0 + row) * LL + l) * DD + g8 * 8;
            float4 v0 = *(const float4*)src;
            float4 v1 = *(const float4*)(src + 4);
            bf16x8 pk;
            pk[0]=(short)f2bf(v0.x); pk[1]=(short)f2bf(v0.y); pk[2]=(short)f2bf(v0.z); pk[3]=(short)f2bf(v0.w);
            pk[4]=(short)f2bf(v1.x); pk[5]=(short)f2bf(v1.y); pk[6]=(short)f2bf(v1.z); pk[7]=(short)f2bf(v1.w);
            *(bf16x8*)&Asw[(row * 8 + (g8 ^ (row & 7))) * 8] = pk;
        }
        __syncthreads();

        f32x4 acc[8][4];
#pragma unroll
        for (int mf = 0; mf < 8; mf++)
#pragma unroll
            for (int nf = 0; nf < 4; nf++) acc[mf][nf] = (f32x4){0.f,0.f,0.f,0.f};

#pragma unroll
        for (int k0 = 0; k0 < 2; k0++){
#pragma unroll
            for (int mf = 0; mf < 8; mf++){
                int row = mf * 16 + col;
                bf16x8 a = *(const bf16x8*)&Asw[(row * 8 + ((k0 * 4 + grp) ^ (row & 7))) * 8];
#pragma unroll
                for (int nf = 0; nf < 4; nf++)
                    acc[mf][nf] = __builtin_amdgcn_mfma_f32_16x16x32_bf16(a, bfr[k0][nf], acc[mf][nf], 0, 0, 0);
            }
        }
        __syncthreads();

#pragma unroll
        for (int mf = 0; mf < 8; mf++){
#pragma unroll
            for (int nf = 0; nf < 4; nf++)
#pragma unroll
                for (int r = 0; r < 4; r++)
                    obuf[w][(grp * 4 + r) * 64 + nf * 16 + col] = acc[mf][nf][r];
#pragma unroll
            for (int p = 0; p < 2; p++){
                int rloc = p * 8 + (lane >> 3);
                int c0 = (lane & 7) * 8;
                float4 r0 = *(const float4*)&obuf[w][rloc * 64 + c0];
                float4 r1 = *(const float4*)&obuf[w][rloc * 64 + c0 + 4];
                int m = m0 + mf * 16 + rloc;
                if (m < NIMG){
                    int b = m / NT, tt = m % NT;
                    int jj8 = j0 + w * 64 + c0;
                    int gg2 = jj8 >> 7, jjl = jj8 & 127;
                    bf16x8 pk;
                    pk[0]=(short)f2bf(r0.x); pk[1]=(short)f2bf(r0.y); pk[2]=(short)f2bf(r0.z); pk[3]=(short)f2bf(r0.w);
                    pk[4]=(short)f2bf(r1.x); pk[5]=(short)f2bf(r1.y); pk[6]=(short)f2bf(r1.z); pk[7]=(short)f2bf(r1.w);
                    *(bf16x8*)&G[(((size_t)(b * GPB + gg2) * NT + tt) * LL + l) * 128 + jjl] = pk;
                }
            }
        }
    }
}

// ---------------- persistent scan: 64 gates blocks, local redundant attention ----------------
// Block (b,g): owns units [g*32,(g+1)*32) of batch b. Per step: wait own-batch ctr (h(t-1)
// complete), stage h, compute alpha(b,t) LOCALLY (redundant across the 16 blocks of batch b;
// bit-identical — same deterministic code on same inputs), then alpha·G + whh·h for its jj
// span, local LSTM pointwise (cx in LDS), publish 32-float h-slice + ctr++.
// ONE L3 sync event per step.
__global__ __launch_bounds__(256) void scan_pc(
    const u16* __restrict__ G, const u16* __restrict__ whh_p,
    const float* __restrict__ bsum, const float* __restrict__ proj,
    const float* __restrict__ w_wT, const float* __restrict__ w_b,
    const float* __restrict__ waw, const float* __restrict__ wab,
    float* __restrict__ hx_g, unsigned int* __restrict__ ctr,
    float* __restrict__ hseq)
{
    __shared__ float projL[LL * DD];   // 60KB proj(b,t)
    __shared__ float hxs[HID];         // 2KB
    __shared__ float als[LL];          // 960B
    __shared__ float esl[LL];          // 960B
    __shared__ float apjs[DD];         // 256B
    __shared__ float scr[256];         // 1KB gemv partials
    __shared__ float red[8][128];      // 4KB
    __shared__ float gat[128];         // 512B
    __shared__ float cxl[32];          // 128B

    int tid = threadIdx.x, blk = blockIdx.x;
    int b = blk & 3, g = blk >> 2;
    int jq = tid & 31, lg = tid >> 5;
    float wb0 = wab[0];
    const size_t SLICE = (size_t)LL * 128;
    const u16* gbase0 = G + ((size_t)(b * GPB + g) * NT) * SLICE;
    const float* projb = proj + (size_t)b * NT * LL * DD;

    if (tid < 32) cxl[tid] = 0.f;

    // prefetch G(0) into own-XCD L2 (coalesced)
    {
        float sink = 0.f;
        const float4* pp = (const float4*)(gbase0);
#pragma unroll
        for (int i = 0; i < 15; i++){ float4 v = pp[i * 256 + tid]; sink += v.x + v.w; }
        asm volatile("" :: "v"(sink));
    }

    for (int t = 0; t < NT; t++){
        // ---- sync: h(t-1) complete ----
        if (t == 0){
            hxs[tid] = 0.f; hxs[tid + 256] = 0.f;
        } else {
            if (tid == 0){
                unsigned int tgt = 16u * (unsigned int)t;
                int gu = 0;
                while (aldu(&ctr[b * 32]) < tgt){
                    if (++gu > (1 << 24)) break;
                    __builtin_amdgcn_s_sleep(1);
                }
            }
            __syncthreads();
            const float* hsrc = hx_g + (size_t)(t & 1) * (NB * HID) + b * HID;
            hxs[tid] = ald(&hsrc[tid]);
            hxs[tid + 256] = ald(&hsrc[tid + 256]);
        }
        // stage proj(b,t) into LDS (L2-hot from prefetch); independent of hxs
        {
            const float* src = projb + (size_t)t * LL * DD;
            for (int it = 0; it < 15; it++){
                int idx = it * 256 + tid;
                *(float4*)&projL[idx * 4] = *(const float4*)&src[idx * 4];
            }
        }
        __syncthreads();

        // ---- local attention: apj gemv (4-way k split) ----
        {
            int dd = tid & 63, dq = tid >> 6;
            float p = 0.f;
            for (int ki = 0; ki < 128; ki++){
                int k = dq * 128 + ki;
                p = fmaf(hxs[k], w_wT[k * 64 + dd], p);
            }
            scr[dq * 64 + dd] = p;
        }
        __syncthreads();
        if (tid < 64) apjs[tid] = w_b[tid] + scr[tid] + scr[64 + tid] + scr[128 + tid] + scr[192 + tid];
        __syncthreads();
        if (tid < LL){
            const float* pr = &projL[tid * DD];
            float e = 0.f;
#pragma unroll
            for (int d = 0; d < DD; d++) e = fmaf(tanh_f(pr[d] + apjs[d]), waw[d], e);
            esl[tid] = e + wb0;
        }
        __syncthreads();
        if (tid < 64){
            float m = -1e30f;
            for (int l = tid; l < LL; l += 64) m = fmaxf(m, esl[l]);
#pragma unroll
            for (int off = 32; off; off >>= 1) m = fmaxf(m, __shfl_xor(m, off));
            float ex[4]; int c = 0; float ssum = 0.f;
            for (int l = tid; l < LL; l += 64){ float e2 = __expf(esl[l] - m); ex[c++] = e2; ssum += e2; }
#pragma unroll
            for (int off = 32; off; off >>= 1) ssum += __shfl_xor(ssum, off);
            float inv = 1.f / ssum; c = 0;
            for (int l = tid; l < LL; l += 64) als[l] = ex[c++] * inv;
        }
        __syncthreads();

        // ---- gates: alpha*G (30 l, L2-hot) + whh*h (64 k) ----
        float ac0 = 0.f, ac1 = 0.f, ac2 = 0.f, ac3 = 0.f;
        {
            const u16* gp = gbase0 + (size_t)t * SLICE + (size_t)(lg * 30) * 128 + jq * 4;
#pragma unroll 6
            for (int i = 0; i < 30; i++){
                short4 gv = *(const short4*)(gp + i * 128);
                float al = als[lg * 30 + i];
                ac0 = fmaf(al, bf2f((u16)gv.x), ac0);
                ac1 = fmaf(al, bf2f((u16)gv.y), ac1);
                ac2 = fmaf(al, bf2f((u16)gv.z), ac2);
                ac3 = fmaf(al, bf2f((u16)gv.w), ac3);
            }
            const u16* wp = whh_p + (size_t)(lg * 64) * NJ + g * 128 + jq * 4;
#pragma unroll 8
            for (int ki = 0; ki < 64; ki++){
                short4 wv = *(const short4*)(wp + (size_t)ki * NJ);
                float h = hxs[lg * 64 + ki];
                ac0 = fmaf(h, bf2f((u16)wv.x), ac0);
                ac1 = fmaf(h, bf2f((u16)wv.y), ac1);
                ac2 = fmaf(h, bf2f((u16)wv.z), ac2);
                ac3 = fmaf(h, bf2f((u16)wv.w), ac3);
            }
        }
        red[lg][jq * 4 + 0] = ac0;
        red[lg][jq * 4 + 1] = ac1;
        red[lg][jq * 4 + 2] = ac2;
        red[lg][jq * 4 + 3] = ac3;
        __syncthreads();
        if (tid < 128){
            float v = 0.f;
#pragma unroll
            for (int q = 0; q < 8; q++) v += red[q][tid];
            gat[tid] = v;
        }
        __syncthreads();

        // ---- local pointwise cell for units [g*32, g*32+32) ----
        if (tid < 32){
            int jjb = g * 128 + tid * 4;
            float4 bs = *(const float4*)&bsum[jjb];
            float gi = gat[tid*4 + 0] + bs.x;
            float gf = gat[tid*4 + 1] + bs.y;
            float gg = gat[tid*4 + 2] + bs.z;
            float go = gat[tid*4 + 3] + bs.w;
            float c = sigm(gf) * cxl[tid] + sigm(gi) * tanhf(gg);
            cxl[tid] = c;
            float h = sigm(go) * tanhf(c);
            int u = g * 32 + tid;
            ast(&hx_g[(size_t)((t + 1) & 1) * (NB * HID) + b * HID + u], h);
            hseq[((size_t)t * NB + b) * HID + u] = h;
        }
        __syncthreads();          // drains h stores (vmcnt 0 before barrier)
        if (tid == 0)
            __hip_atomic_fetch_add(&ctr[b * 32], 1u, __ATOMIC_RELAXED, __HIP_MEMORY_SCOPE_AGENT);

        // ---- prefetch G(t+1) + proj(t+1) (overlap next sync wait) ----
        if (t < NT - 1){
            float sink = 0.f;
            const float4* pp = (const float4*)(gbase0 + (size_t)(t + 1) * SLICE);
#pragma unroll
            for (int i = 0; i < 15; i++){ float4 v = pp[i * 256 + tid]; sink += v.x + v.w; }
            const float4* qq = (const float4*)(projb + (size_t)(t + 1) * LL * DD);
#pragma unroll
            for (int i = 0; i < 15; i++){ float4 v = qq[i * 256 + tid]; sink += v.x + v.w; }
            asm volatile("" :: "v"(sink));
        }
    }
}

// ---------------- MLP heads ----------------
__global__ __launch_bounds__(256) void mlp_kernel(
    const float* __restrict__ hseq,
    const float* __restrict__ sw1T, const float* __restrict__ sb1,
    const float* __restrict__ sw2,  const float* __restrict__ sb2,
    const float* __restrict__ sw3,  const float* __restrict__ sb3,
    const float* __restrict__ sw4,  const float* __restrict__ sb4,
    const float* __restrict__ vw1T, const float* __restrict__ vb1,
    const float* __restrict__ vw2,  const float* __restrict__ vb2,
    const float* __restrict__ vw3,  const float* __restrict__ vb3,
    const float* __restrict__ vw4,  const float* __restrict__ vb4,
    float* __restrict__ out)
{
    __shared__ float h0[HID];
    __shared__ float h1[2][100];
    __shared__ float h2[2][52];
    __shared__ float h3[2][12];
    int tb = blockIdx.x;
    int tid = threadIdx.x;
    for (int i = tid; i < HID; i += 256) h0[i] = hseq[(size_t)tb * HID + i];
    __syncthreads();
    if (tid < 100){
        float a = sb1[tid];
        for (int k = 0; k < HID; k++) a = fmaf(h0[k], sw1T[k*100 + tid], a);
        h1[0][tid] = fmaxf(a, 0.f);
    } else if (tid >= 128 && tid < 228){
        int u = tid - 128;
        float a = vb1[u];
        for (int k = 0; k < HID; k++) a = fmaf(h0[k], vw1T[k*100 + u], a);
        h1[1][u] = fmaxf(a, 0.f);
    }
    __syncthreads();
    if (tid < 50){
        float a = sb2[tid];
        for (int k = 0; k < 100; k++) a = fmaf(h1[0][k], sw2[tid*100 + k], a);
        h2[0][tid] = fmaxf(a, 0.f);
    } else if (tid >= 128 && tid < 178){
        int u = tid - 128;
        float a = vb2[u];
        for (int k = 0; k < 100; k++) a = fmaf(h1[1][k], vw2[u*100 + k], a);
        h2[1][u] = fmaxf(a, 0.f);
    }
    __syncthreads();
    if (tid < 10){
        float a = sb3[tid];
        for (int k = 0; k < 50; k++) a = fmaf(h2[0][k], sw3[tid*50 + k], a);
        h3[0][tid] = fmaxf(a, 0.f);
    } else if (tid >= 128 && tid < 138){
        int u = tid - 128;
        float a = vb3[u];
        for (int k = 0; k < 50; k++) a = fmaf(h2[1][k], vw3[u*50 + k], a);
        h3[1][u] = fmaxf(a, 0.f);
    }
    __syncthreads();
    if (tid == 0){
        float a = sb4[0];
        for (int k = 0; k < 10; k++) a = fmaf(h3[0][k], sw4[k], a);
        out[tb] = a;
    } else if (tid == 128){
        float a = vb4[0];
        for (int k = 0; k < 10; k++) a = fmaf(h3[1][k], vw4[k], a);
        out[360 + tb] = a;
    }
}

extern "C" void kernel_launch(void* const* d_in, const int* in_sizes, int n_in,
                              void* d_out, int out_size, void* d_ws, size_t ws_size,
                              hipStream_t stream)
{
    (void)in_sizes; (void)n_in; (void)out_size;
    if (ws_size < WS_NEEDED) return;

    const float* cam   = (const float*)d_in[0];
    const float* cw1   = (const float*)d_in[1];  const float* cb1 = (const float*)d_in[2];
    const float* cw2   = (const float*)d_in[3];  const float* cb2 = (const float*)d_in[4];
    const float* cw3   = (const float*)d_in[5];  const float* cb3 = (const float*)d_in[6];
    const float* cw4   = (const float*)d_in[7];  const float* cb4 = (const float*)d_in[8];
    const float* cw5   = (const float*)d_in[9];  const float* cb5 = (const float*)d_in[10];
    const float* pw    = (const float*)d_in[11]; const float* pb  = (const float*)d_in[12];
    const float* w_w   = (const float*)d_in[13]; const float* w_b = (const float*)d_in[14];
    const float* waw   = (const float*)d_in[15]; const float* wab = (const float*)d_in[16];
    const float* wih   = (const float*)d_in[17]; const float* whh = (const float*)d_in[18];
    const float* bih   = (const float*)d_in[19]; const float* bhh = (const float*)d_in[20];
    const float* sw1   = (const float*)d_in[21]; const float* sb1 = (const float*)d_in[22];
    const float* sw2   = (const float*)d_in[23]; const float* sb2 = (const float*)d_in[24];
    const float* sw3   = (const float*)d_in[25]; const float* sb3 = (const float*)d_in[26];
    const float* sw4   = (const float*)d_in[27]; const float* sb4 = (const float*)d_in[28];
    const float* vw1   = (const float*)d_in[29]; const float* vb1 = (const float*)d_in[30];
    const float* vw2   = (const float*)d_in[31]; const float* vb2 = (const float*)d_in[32];
    const float* vw3   = (const float*)d_in[33]; const float* vb3 = (const float*)d_in[34];
    const float* vw4   = (const float*)d_in[35]; const float* vb4 = (const float*)d_in[36];

    char* ws = (char*)d_ws;
    u16*   camcl = (u16*)(ws + CAMCL_OFF);
    u16*   a1    = (u16*)(ws + A1_OFF);
    u16*   a2    = (u16*)(ws + A2_OFF);
    u16*   a3    = (u16*)(ws + A3_OFF);
    u16*   a4    = (u16*)(ws + A4_OFF);
    u16*   a5    = (u16*)(ws + A5_OFF);
    u16*   w1b   = (u16*)(ws + W1B_OFF);
    u16*   w2b   = (u16*)(ws + W2B_OFF);
    u16*   w3b   = (u16*)(ws + W3B_OFF);
    u16*   w4b   = (u16*)(ws + W4B_OFF);
    u16*   w5b   = (u16*)(ws + W5B_OFF);
    float* feats = (float*)(ws + FEATS_OFF);
    float* proj  = (float*)(ws + PROJ_OFF);
    float* w_wT  = (float*)(ws + WWT_OFF);
    u16*   whh_p = (u16*)  (ws + WHHP_OFF);
    float* bsum  = (float*)(ws + BSUM_OFF);
    float* sw1T  = (float*)(ws + SW1T_OFF);
    float* vw1T  = (float*)(ws + VW1T_OFF);
    float* hx_g  = (float*)(ws + SC_HX);
    unsigned int* ctr = (unsigned int*)(ws + SC_CTR);
    float* hseq  = (float*)(ws + HSEQ_OFF);
    u16*   G     = (u16*)  (ws + G_OFF);

    cam_to_cl<<<(NIMG*96*160 + 255)/256, 256, 0, stream>>>(cam, camcl);
    prep_wbf<<<64, 256, 0, stream>>>(cw1, w1b, 24,  3,  8, 5, 28, 32);
    prep_wbf<<<64, 256, 0, stream>>>(cw2, w2b, 36, 24, 24, 5, 28, 48);
    prep_wbf<<<64, 256, 0, stream>>>(cw3, w3b, 48, 36, 40, 5, 28, 48);
    prep_wbf<<<64, 256, 0, stream>>>(cw4, w4b, 64, 48, 48, 3, 10, 64);
    prep_wbf<<<64, 256, 0, stream>>>(cw5, w5b, 64, 64, 64, 3,  9, 64);

    conv_mfma<   8,    32,   24,  24,   5,  28,   2, 2, 96, 160, 48, 80,  8, 40>
        <<<dim3(12, NIMG), 256, 0, stream>>>(camcl, w1b, cb1, a1);
    conv_mfma<  24,    48,   36,  40,   5,  28,   2, 2, 48,  80, 24, 40,  8, 20>
        <<<dim3(6, NIMG), 256, 0, stream>>>(a1, w2b, cb2, a2);
    conv_mfma<  40,    48,   48,  48,   5,  28,   2, 2, 24,  40, 12, 20, 12, 20>
        <<<dim3(1, NIMG), 256, 0, stream>>>(a2, w3b, cb3, a3);
    conv_mfma<  48,    64,   64,  64,   3,  10,   1, 1, 12,  20, 12, 20, 12, 20>
        <<<dim3(1, NIMG), 256, 0, stream>>>(a3, w4b, cb4, a4);
    conv_mfma<  64,    64,   64,  64,   3,   9,   1, 1, 12,  20, 12, 20, 12, 20>
        <<<dim3(1, NIMG), 256, 0, stream>>>(a4, w5b, cb5, a5);

    extract_feats<<<(NIMG*12*20*64 + 255)/256, 256, 0, stream>>>(a5, feats);
    proj_kernel<<<NIMG*LL/4, 256, 0, stream>>>(feats, pw, pb, proj);
    prep<<<1024, 256, 0, stream>>>(w_w, whh, bih, bhh, w_wT, whh_p, bsum);
    gcompute_mfma2<<<dim3(8, 240), 256, 0, stream>>>(feats, wih, G);

    // zero scan state: hx parity buffers(16KB) + ctr(512B)  (re-zeroed every replay)
    hipMemsetAsync(ws + SC_HX, 0, 16896, stream);

    scan_pc<<<TBLK, 256, 0, stream>>>(G, whh_p, bsum, proj, w_wT, w_b, waw, wab,
                                      hx_g, ctr, hseq);

    prep2<<<256, 256, 0, stream>>>(sw1, vw1, sw1T, vw1T);

    mlp_kernel<<<360, 256, 0, stream>>>(hseq,
        sw1T, sb1, sw2, sb2, sw3, sb3, sw4, sb4,
        vw1T, vb1, vw2, vb2, vw3, vb3, vw4, vb4, (float*)d_out);
}

// Round 12
// 1864.771 us; speedup vs baseline: 1.0250x; 1.0250x over previous
//
#include <hip/hip_runtime.h>
#include <hip/hip_bf16.h>

typedef unsigned short u16;
using bf16x8 = __attribute__((ext_vector_type(8))) short;
using f32x4  = __attribute__((ext_vector_type(4))) float;

#define NB   4
#define NT   90
#define NIMG 360
#define LL   240
#define DD   64
#define HID  512
#define NJ   2048
#define GPB  16            // gates blocks per batch
#define TBLK (NB * GPB)    // 64 blocks

#define DEV __device__ __forceinline__

DEV float bf2f(u16 x){ unsigned int u = ((unsigned int)x) << 16; float f; __builtin_memcpy(&f, &u, 4); return f; }
DEV u16 f2bf(float f){ unsigned int u; __builtin_memcpy(&u, &f, 4); unsigned int r = (u + 0x7FFFu + ((u >> 16) & 1u)) >> 16; return (u16)r; }
DEV float sigm(float x){ return 1.f / (1.f + __expf(-x)); }
DEV float tanh_f(float x){ x = fminf(fmaxf(x, -15.f), 15.f); float e = __expf(2.f*x); return (e - 1.f) / (e + 1.f); }

// L3-coherent (agent-scope, relaxed) accessors for cross-XCD mutable state.
DEV void  ast(float* p, float v){ __hip_atomic_store(p, v, __ATOMIC_RELAXED, __HIP_MEMORY_SCOPE_AGENT); }
DEV float ald(const float* p){ return __hip_atomic_load(p, __ATOMIC_RELAXED, __HIP_MEMORY_SCOPE_AGENT); }
DEV void  astu(unsigned int* p, unsigned int v){ __hip_atomic_store(p, v, __ATOMIC_RELAXED, __HIP_MEMORY_SCOPE_AGENT); }
DEV unsigned int aldu(const unsigned int* p){ return __hip_atomic_load(p, __ATOMIC_RELAXED, __HIP_MEMORY_SCOPE_AGENT); }

// ---------------- workspace layout (bytes) ----------------
// G2 layout: [b][g(16)][t(90)][l(240)][128 jj] u16 — block (b,g) slice at step t is one
// contiguous 61,440B run.
static const size_t G_OFF     = 0;            // 353,894,400 B
static const size_t CAMCL_OFF = 0;            // conv temporaries alias over G
static const size_t A1_OFF    = 88473600;
static const size_t A2_OFF    = 154828800;
static const size_t A3_OFF    = 182476800;
static const size_t A4_OFF    = 190771200;
static const size_t A5_OFF    = 201830400;
static const size_t W1B_OFF   = 212889600;
static const size_t W2B_OFF   = 212903936;
static const size_t W3B_OFF   = 212968448;
static const size_t W4B_OFF   = 213075968;
static const size_t W5B_OFF   = 213137408;
static const size_t FEATS_OFF = 353894400;    // fp32 [360][240][64]; dead during scan
static const size_t SC_HX     = 353898496;    // fp32 [2][4][512] = 16KB (parity double-buffer)
static const size_t SC_FLG    = 353914880;    // u32 [4][32]: flags[b*32+g], one 128B line per batch
static const size_t PROJ_OFF  = 376012800;    // fp32 [360][240][64]
static const size_t WWT_OFF   = 398131200;    // fp32 [512][64]   w_w^T
static const size_t WHHP_OFF  = 398262272;    // bf16 [512][2048] whh^T, j-permuted
static const size_t BSUM_OFF  = 400359424;    // fp32 [2048] bih+bhh, j-permuted
static const size_t SW1T_OFF  = 400367616;    // fp32 [512][100]
static const size_t VW1T_OFF  = 400572416;    // fp32 [512][100]
static const size_t HSEQ_OFF  = 400809984;    // fp32 [90][4][512]
static const size_t WS_NEEDED = 401547264;

// ---------------- camera NCHW fp32 -> channels-last bf16 [n][h][w][8] ----------------
__global__ __launch_bounds__(256) void cam_to_cl(const float* __restrict__ cam, u16* __restrict__ out)
{
    int i = blockIdx.x * 256 + threadIdx.x;
    if (i >= NIMG * 96 * 160) return;
    int hw = i % (96 * 160);
    int n  = i / (96 * 160);
    const float* p = cam + (size_t)n * 3 * 96 * 160 + hw;
    bf16x8 v;
    v[0] = (short)f2bf(p[0]);
    v[1] = (short)f2bf(p[15360]);
    v[2] = (short)f2bf(p[30720]);
    v[3] = 0; v[4] = 0; v[5] = 0; v[6] = 0; v[7] = 0;
    *(bf16x8*)&out[(size_t)i * 8] = v;
}

// ---------------- weight prep for convs ----------------
__global__ __launch_bounds__(256) void prep_wbf(
    const float* __restrict__ w, u16* __restrict__ wbf,
    int COUT, int CIN, int CI_PAD, int KHW, int CELLS_PAD, int M_PAD)
{
    int K_PAD = CELLS_PAD * CI_PAD;
    int total = M_PAD * K_PAD;
    for (int i = blockIdx.x * 256 + threadIdx.x; i < total; i += gridDim.x * 256){
        int co = i / K_PAD, kk = i % K_PAD;
        int cell = kk / CI_PAD, ci = kk % CI_PAD;
        float v = 0.f;
        if (co < COUT && cell < KHW * KHW && ci < CIN){
            int kh = cell / KHW, kw = cell % KHW;
            v = w[((size_t)(co * CIN + ci) * KHW + kh) * KHW + kw];
        }
        wbf[i] = f2bf(v);
    }
}

// ---------------- implicit-GEMM MFMA conv (channels-last bf16 in/out) ----------------
template<int CI_PAD, int M_PAD, int COUT, int CO_STORE, int KHW, int CELLS_PAD,
         int S, int P, int HIN, int WIN, int HOUT, int WOUT, int TOH, int TOW>
__global__ __launch_bounds__(256) void conv_mfma(
    const u16* __restrict__ in, const u16* __restrict__ wbf,
    const float* __restrict__ bias, u16* __restrict__ out)
{
    constexpr int K_PAD = CELLS_PAD * CI_PAD;
    constexpr int CP8   = CI_PAD / 8;
    constexpr int TIH   = (TOH - 1) * S + KHW;
    constexpr int TIW   = (TOW - 1) * S + KHW;
    constexpr int TIW_H = (TIW + 1) / 2;
    constexpr int NF    = TOH * TOW / 16;
    constexpr int NK0   = K_PAD / 32;
    constexpr int MF    = M_PAD / 16;
    constexpr int NPW   = (NF + 3) / 4;
    constexpr int LDSE  = (S == 2) ? TIH * CP8 * 2 * TIW_H * 8 : TIH * CP8 * TIW * 8;
    static_assert((TOH * TOW) % 16 == 0, "N tile");
    static_assert(K_PAD % 32 == 0, "K pad");

    __shared__ u16 lds[LDSE];

    int tile = blockIdx.x, n = blockIdx.y;
    constexpr int TW_T = WOUT / TOW;
    int th = tile / TW_T, tw = tile % TW_T;
    int oh0 = th * TOH, ow0 = tw * TOW;
    int ih0 = oh0 * S - P, iw0 = ow0 * S - P;
    int tid = threadIdx.x;

    constexpr int CHUNKS = TIH * TIW * CP8;
    for (int i = tid; i < CHUNKS; i += 256){
        int c8 = i % CP8; int r2 = i / CP8;
        int iw = r2 % TIW, ih = r2 / TIW;
        int ihg = ih0 + ih, iwg = iw0 + iw;
        bf16x8 v = {0,0,0,0,0,0,0,0};
        if (ihg >= 0 && ihg < HIN && iwg >= 0 && iwg < WIN)
            v = *(const bf16x8*)&in[(((size_t)n * HIN + ihg) * WIN + iwg) * CI_PAD + c8 * 8];
        int off;
        if (S == 2) off = (((ih * CP8 + c8) * 2 + (iw & 1)) * TIW_H + (iw >> 1)) * 8;
        else        off = ((ih * CP8 + c8) * TIW + iw) * 8;
        *(bf16x8*)&lds[off] = v;
    }
    __syncthreads();

    int lane = tid & 63, wv = tid >> 6;
    int col = lane & 15, grp = lane >> 4;

    int ihb[NPW], iwb[NPW];
    bool act[NPW];
#pragma unroll
    for (int i2 = 0; i2 < NPW; i2++){
        int nf = wv + i2 * 4;
        act[i2] = (nf < NF);
        int nfc = act[i2] ? nf : 0;
        int nsp = nfc * 16 + col;
        ihb[i2] = (nsp / TOW) * S;
        iwb[i2] = (nsp % TOW) * S;
    }

    f32x4 acc[MF][NPW];
#pragma unroll
    for (int mf = 0; mf < MF; mf++)
#pragma unroll
        for (int i2 = 0; i2 < NPW; i2++)
            acc[mf][i2] = (f32x4){0.f, 0.f, 0.f, 0.f};

    for (int k0 = 0; k0 < NK0; k0++){
        bf16x8 a[MF];
#pragma unroll
        for (int mf = 0; mf < MF; mf++)
            a[mf] = *(const bf16x8*)&wbf[(size_t)(mf * 16 + col) * K_PAD + k0 * 32 + grp * 8];
        int k8 = k0 * 32 + grp * 8;
        int cell = k8 / CI_PAD;
        int ci0  = k8 - cell * CI_PAD;
        if (cell >= KHW * KHW) cell = 0;
        int kh = cell / KHW, kw = cell - (cell / KHW) * KHW;
        int cb = ci0 >> 3;
#pragma unroll
        for (int i2 = 0; i2 < NPW; i2++){
            if (!act[i2]) continue;
            int ih = ihb[i2] + kh;
            int off;
            if (S == 2) off = (((ih * CP8 + cb) * 2 + (kw & 1)) * TIW_H + (iwb[i2] >> 1) + (kw >> 1)) * 8;
            else        off = ((ih * CP8 + cb) * TIW + iwb[i2] + kw) * 8;
            bf16x8 b = *(const bf16x8*)&lds[off];
#pragma unroll
            for (int mf = 0; mf < MF; mf++)
                acc[mf][i2] = __builtin_amdgcn_mfma_f32_16x16x32_bf16(a[mf], b, acc[mf][i2], 0, 0, 0);
        }
    }

#pragma unroll
    for (int i2 = 0; i2 < NPW; i2++){
        if (!act[i2]) continue;
        int nf = wv + i2 * 4;
        int nsp = nf * 16 + col;
        int oh = oh0 + nsp / TOW, ow = ow0 + nsp % TOW;
        size_t obase = (((size_t)n * HOUT + oh) * WOUT + ow) * CO_STORE;
#pragma unroll
        for (int mf = 0; mf < MF; mf++){
            int cobase = mf * 16 + grp * 4;
#pragma unroll
            for (int r = 0; r < 4; r++){
                int co = cobase + r;
                if (co < CO_STORE){
                    float x = (co < COUT) ? fmaxf(acc[mf][i2][r] + bias[co], 0.f) : 0.f;
                    out[obase + co] = f2bf(x);
                }
            }
        }
    }
}

// ---------------- feats rearrange ----------------
__global__ __launch_bounds__(256) void extract_feats(const u16* __restrict__ a5, float* __restrict__ feats)
{
    int idx = blockIdx.x * 256 + threadIdx.x;
    if (idx >= NIMG * 12 * 20 * 64) return;
    int c = idx & 63; int t1 = idx >> 6;
    int w = t1 % 20; t1 /= 20;
    int h = t1 % 12; int n = t1 / 12;
    float v = bf2f(a5[idx]);
    int flat = w * 768 + c * 12 + h;
    int d = flat / 240, l = flat % 240;
    feats[((size_t)n * LL + l) * DD + d] = v;
}

// ---------------- proj = feats @ proj_w.T + proj_b ----------------
__global__ __launch_bounds__(256) void proj_kernel(
    const float* __restrict__ feats, const float* __restrict__ pw,
    const float* __restrict__ pb, float* __restrict__ proj)
{
    __shared__ float pws[64][65];
    __shared__ float fs[4][64];
    int tid = threadIdx.x;
    size_t R0 = (size_t)blockIdx.x * 4;
    for (int i = tid; i < 4096; i += 256){
        int dd = i / 64, d = i % 64;
        pws[d][dd] = pw[dd*64 + d];
    }
    { int r = tid / 64, d = tid % 64; fs[r][d] = feats[(R0 + r)*64 + d]; }
    __syncthreads();
    int r = tid / 64, dd = tid % 64;
    float a = pb[dd];
    for (int d = 0; d < 64; d++) a = fmaf(fs[r][d], pws[d][dd], a);
    proj[(R0 + r)*64 + dd] = a;
}

// ---------------- prep: whh permute, bias combine, w_w transpose ----------------
__global__ __launch_bounds__(256) void prep(
    const float* __restrict__ w_w, const float* __restrict__ whh,
    const float* __restrict__ bih, const float* __restrict__ bhh,
    float* __restrict__ w_wT, u16* __restrict__ whh_p, float* __restrict__ bsum)
{
    int idx = blockIdx.x * 256 + threadIdx.x;
    int stride = gridDim.x * 256;
    for (int i = idx; i < 512*64; i += stride){
        int k = i / 64, dd = i % 64;
        w_wT[i] = w_w[dd*512 + k];
    }
    for (int i = idx; i < 512*2048; i += stride){
        int k = i / 2048, jj = i % 2048;
        int u = jj >> 2, g = jj & 3, j = g*512 + u;
        whh_p[i] = f2bf(whh[(size_t)j*512 + k]);
    }
    for (int i = idx; i < 2048; i += stride){
        int u = i >> 2, g = i & 3, j = g*512 + u;
        bsum[i] = bih[j] + bhh[j];
    }
}

// ---------------- prep2: MLP first-layer transposes ----------------
__global__ __launch_bounds__(256) void prep2(
    const float* __restrict__ sw1, const float* __restrict__ vw1,
    float* __restrict__ sw1T, float* __restrict__ vw1T)
{
    int idx = blockIdx.x * 256 + threadIdx.x;
    int stride = gridDim.x * 256;
    for (int i = idx; i < 512*100; i += stride){
        int k = i / 100, u = i % 100;
        sw1T[i] = sw1[u*512 + k];
        vw1T[i] = vw1[u*512 + k];
    }
}

// ---------------- gcompute via MFMA; G2 slice-contiguous layout ----------------
__global__ __launch_bounds__(256, 2) void gcompute_mfma2(
    const float* __restrict__ feats, const float* __restrict__ wih, u16* __restrict__ G)
{
    __shared__ u16 Bsw[256 * 64];
    __shared__ u16 Asw[128 * 64];
    float (*obuf)[1024] = (float(*)[1024])Asw;

    int jt = blockIdx.x, l = blockIdx.y;
    int j0 = jt * 256;
    int tid = threadIdx.x;
    int g8 = tid & 7;

    for (int p = 0; p < 8; p++){
        int row = p * 32 + (tid >> 3);
        int jj = j0 + row;
        int j = (jj & 3) * 512 + (jj >> 2);
        const float* src = wih + (size_t)j * 15360 + l * 64 + g8 * 8;
        float4 v0 = *(const float4*)src;
        float4 v1 = *(const float4*)(src + 4);
        bf16x8 pk;
        pk[0]=(short)f2bf(v0.x); pk[1]=(short)f2bf(v0.y); pk[2]=(short)f2bf(v0.z); pk[3]=(short)f2bf(v0.w);
        pk[4]=(short)f2bf(v1.x); pk[5]=(short)f2bf(v1.y); pk[6]=(short)f2bf(v1.z); pk[7]=(short)f2bf(v1.w);
        *(bf16x8*)&Bsw[(row * 8 + (g8 ^ (row & 7))) * 8] = pk;
    }
    __syncthreads();

    int lane = tid & 63, w = tid >> 6;
    int col = lane & 15, grp = lane >> 4;

    bf16x8 bfr[2][4];
#pragma unroll
    for (int k0 = 0; k0 < 2; k0++)
#pragma unroll
        for (int nf = 0; nf < 4; nf++){
            int row = w * 64 + nf * 16 + col;
            bfr[k0][nf] = *(const bf16x8*)&Bsw[(row * 8 + ((k0 * 4 + grp) ^ (row & 7))) * 8];
        }

    for (int mt = 0; mt < 3; mt++){
        int m0 = mt * 128;
        __syncthreads();
        for (int p = 0; p < 4; p++){
            int row = p * 32 + (tid >> 3);
            const float* src = feats + ((size_t)(m0 + row) * LL + l) * DD + g8 * 8;
            float4 v0 = *(const float4*)src;
            float4 v1 = *(const float4*)(src + 4);
            bf16x8 pk;
            pk[0]=(short)f2bf(v0.x); pk[1]=(short)f2bf(v0.y); pk[2]=(short)f2bf(v0.z); pk[3]=(short)f2bf(v0.w);
            pk[4]=(short)f2bf(v1.x); pk[5]=(short)f2bf(v1.y); pk[6]=(short)f2bf(v1.z); pk[7]=(short)f2bf(v1.w);
            *(bf16x8*)&Asw[(row * 8 + (g8 ^ (row & 7))) * 8] = pk;
        }
        __syncthreads();

        f32x4 acc[8][4];
#pragma unroll
        for (int mf = 0; mf < 8; mf++)
#pragma unroll
            for (int nf = 0; nf < 4; nf++) acc[mf][nf] = (f32x4){0.f,0.f,0.f,0.f};

#pragma unroll
        for (int k0 = 0; k0 < 2; k0++){
#pragma unroll
            for (int mf = 0; mf < 8; mf++){
                int row = mf * 16 + col;
                bf16x8 a = *(const bf16x8*)&Asw[(row * 8 + ((k0 * 4 + grp) ^ (row & 7))) * 8];
#pragma unroll
                for (int nf = 0; nf < 4; nf++)
                    acc[mf][nf] = __builtin_amdgcn_mfma_f32_16x16x32_bf16(a, bfr[k0][nf], acc[mf][nf], 0, 0, 0);
            }
        }
        __syncthreads();

#pragma unroll
        for (int mf = 0; mf < 8; mf++){
#pragma unroll
            for (int nf = 0; nf < 4; nf++)
#pragma unroll
                for (int r = 0; r < 4; r++)
                    obuf[w][(grp * 4 + r) * 64 + nf * 16 + col] = acc[mf][nf][r];
#pragma unroll
            for (int p = 0; p < 2; p++){
                int rloc = p * 8 + (lane >> 3);
                int c0 = (lane & 7) * 8;
                float4 r0 = *(const float4*)&obuf[w][rloc * 64 + c0];
                float4 r1 = *(const float4*)&obuf[w][rloc * 64 + c0 + 4];
                int m = m0 + mf * 16 + rloc;
                if (m < NIMG){
                    int b = m / NT, tt = m % NT;
                    int jj8 = j0 + w * 64 + c0;
                    int gg2 = jj8 >> 7, jjl = jj8 & 127;
                    bf16x8 pk;
                    pk[0]=(short)f2bf(r0.x); pk[1]=(short)f2bf(r0.y); pk[2]=(short)f2bf(r0.z); pk[3]=(short)f2bf(r0.w);
                    pk[4]=(short)f2bf(r1.x); pk[5]=(short)f2bf(r1.y); pk[6]=(short)f2bf(r1.z); pk[7]=(short)f2bf(r1.w);
                    *(bf16x8*)&G[(((size_t)(b * GPB + gg2) * NT + tt) * LL + l) * 128 + jjl] = pk;
                }
            }
        }
    }
}

// ---------------- persistent scan: 64 blocks, local attention, flag-line sync ----------------
// Block (b,g): per step, stage proj(b,t) TRANSPOSED (overlaps flag wait), wait the 16 flags
// of batch b at epoch >= t, stage h(t-1), local attention (conflict-free LDS), gates for its
// 128-jj span, local pointwise (cx in LDS), publish 32-float h-slice + flag=t+1.
__global__ __launch_bounds__(256) void scan_pc(
    const u16* __restrict__ G, const u16* __restrict__ whh_p,
    const float* __restrict__ bsum, const float* __restrict__ proj,
    const float* __restrict__ w_wT, const float* __restrict__ w_b,
    const float* __restrict__ waw, const float* __restrict__ wab,
    float* __restrict__ hx_g, unsigned int* __restrict__ flg,
    float* __restrict__ hseq)
{
    __shared__ float projT[DD * 241];  // 61.7KB transposed proj(b,t): [d][l], stride 241
    __shared__ float hxs[HID];         // 2KB
    __shared__ float als[LL];          // 960B
    __shared__ float esl[LL];          // 960B
    __shared__ float apjs[DD];         // 256B
    __shared__ float scr[256];         // 1KB gemv partials
    __shared__ float red[8][128];      // 4KB
    __shared__ float gat[128];         // 512B
    __shared__ float cxl[32];          // 128B

    int tid = threadIdx.x, blk = blockIdx.x;
    int b = blk & 3, g = blk >> 2;
    int jq = tid & 31, lg = tid >> 5;
    float wb0 = wab[0];
    const size_t SLICE = (size_t)LL * 128;
    const u16* gbase0 = G + ((size_t)(b * GPB + g) * NT) * SLICE;
    const float* projb = proj + (size_t)b * NT * LL * DD;

    if (tid < 32) cxl[tid] = 0.f;

    // prefetch G(0) into own-XCD L2 (coalesced)
    {
        float sink = 0.f;
        const float4* pp = (const float4*)(gbase0);
#pragma unroll
        for (int i = 0; i < 15; i++){ float4 v = pp[i * 256 + tid]; sink += v.x + v.w; }
        asm volatile("" :: "v"(sink));
    }

    for (int t = 0; t < NT; t++){
        // ---- stage proj(b,t) transposed (issues before/overlapping the flag wait) ----
        {
            const float* src = projb + (size_t)t * LL * DD;
#pragma unroll
            for (int it = 0; it < 15; it++){
                int idx = it * 256 + tid;           // float4 index in [0,3840)
                int l = idx >> 4, d0 = (idx & 15) * 4;
                float4 v = *(const float4*)&src[l * 64 + d0];
                projT[(d0 + 0) * 241 + l] = v.x;
                projT[(d0 + 1) * 241 + l] = v.y;
                projT[(d0 + 2) * 241 + l] = v.z;
                projT[(d0 + 3) * 241 + l] = v.w;
            }
        }
        // ---- sync: h(t-1) complete (poll 16 flag words, one 128B line) ----
        if (t == 0){
            hxs[tid] = 0.f; hxs[tid + 256] = 0.f;
            __syncthreads();
        } else {
            if (tid < GPB){
                int gu = 0;
                while (aldu(&flg[b * 32 + tid]) < (unsigned int)t){
                    if (++gu > (1 << 24)) break;
                    __builtin_amdgcn_s_sleep(1);
                }
            }
            __syncthreads();
            const float* hsrc = hx_g + (size_t)(t & 1) * (NB * HID) + b * HID;
            hxs[tid] = ald(&hsrc[tid]);
            hxs[tid + 256] = ald(&hsrc[tid + 256]);
            __syncthreads();
        }

        // ---- local attention: apj gemv (4-way k split) ----
        {
            int dd = tid & 63, dq = tid >> 6;
            float p = 0.f;
            for (int ki = 0; ki < 128; ki++){
                int k = dq * 128 + ki;
                p = fmaf(hxs[k], w_wT[k * 64 + dd], p);
            }
            scr[dq * 64 + dd] = p;
        }
        __syncthreads();
        if (tid < 64) apjs[tid] = w_b[tid] + scr[tid] + scr[64 + tid] + scr[128 + tid] + scr[192 + tid];
        __syncthreads();
        if (tid < LL){
            float e = 0.f;
#pragma unroll
            for (int d = 0; d < DD; d++)
                e = fmaf(tanh_f(projT[d * 241 + tid] + apjs[d]), waw[d], e);
            esl[tid] = e + wb0;
        }
        __syncthreads();
        if (tid < 64){
            float m = -1e30f;
            for (int l = tid; l < LL; l += 64) m = fmaxf(m, esl[l]);
#pragma unroll
            for (int off = 32; off; off >>= 1) m = fmaxf(m, __shfl_xor(m, off));
            float ex[4]; int c = 0; float ssum = 0.f;
            for (int l = tid; l < LL; l += 64){ float e2 = __expf(esl[l] - m); ex[c++] = e2; ssum += e2; }
#pragma unroll
            for (int off = 32; off; off >>= 1) ssum += __shfl_xor(ssum, off);
            float inv = 1.f / ssum; c = 0;
            for (int l = tid; l < LL; l += 64) als[l] = ex[c++] * inv;
        }
        __syncthreads();

        // ---- gates: alpha*G (30 l, L2-hot contiguous) + whh*h (64 k) ----
        float ac0 = 0.f, ac1 = 0.f, ac2 = 0.f, ac3 = 0.f;
        {
            const u16* gp = gbase0 + (size_t)t * SLICE + (size_t)(lg * 30) * 128 + jq * 4;
#pragma unroll 6
            for (int i = 0; i < 30; i++){
                short4 gv = *(const short4*)(gp + i * 128);
                float al = als[lg * 30 + i];
                ac0 = fmaf(al, bf2f((u16)gv.x), ac0);
                ac1 = fmaf(al, bf2f((u16)gv.y), ac1);
                ac2 = fmaf(al, bf2f((u16)gv.z), ac2);
                ac3 = fmaf(al, bf2f((u16)gv.w), ac3);
            }
            const u16* wp = whh_p + (size_t)(lg * 64) * NJ + g * 128 + jq * 4;
#pragma unroll 8
            for (int ki = 0; ki < 64; ki++){
                short4 wv = *(const short4*)(wp + (size_t)ki * NJ);
                float h = hxs[lg * 64 + ki];
                ac0 = fmaf(h, bf2f((u16)wv.x), ac0);
                ac1 = fmaf(h, bf2f((u16)wv.y), ac1);
                ac2 = fmaf(h, bf2f((u16)wv.z), ac2);
                ac3 = fmaf(h, bf2f((u16)wv.w), ac3);
            }
        }
        red[lg][jq * 4 + 0] = ac0;
        red[lg][jq * 4 + 1] = ac1;
        red[lg][jq * 4 + 2] = ac2;
        red[lg][jq * 4 + 3] = ac3;
        __syncthreads();
        if (tid < 128){
            float v = 0.f;
#pragma unroll
            for (int q = 0; q < 8; q++) v += red[q][tid];
            gat[tid] = v;
        }
        __syncthreads();

        // ---- local pointwise cell for units [g*32, g*32+32) ----
        if (tid < 32){
            int jjb = g * 128 + tid * 4;
            float4 bs = *(const float4*)&bsum[jjb];
            float gi = gat[tid*4 + 0] + bs.x;
            float gf = gat[tid*4 + 1] + bs.y;
            float gg = gat[tid*4 + 2] + bs.z;
            float go = gat[tid*4 + 3] + bs.w;
            float c = sigm(gf) * cxl[tid] + sigm(gi) * tanhf(gg);
            cxl[tid] = c;
            float h = sigm(go) * tanhf(c);
            int u = g * 32 + tid;
            ast(&hx_g[(size_t)((t + 1) & 1) * (NB * HID) + b * HID + u], h);
            hseq[((size_t)t * NB + b) * HID + u] = h;
        }
        __syncthreads();          // drains h stores (vmcnt 0 before barrier)
        if (tid == 0) astu(&flg[b * 32 + g], (unsigned int)(t + 1));

        // ---- prefetch G(t+1) + proj(t+1) (overlap next sync wait) ----
        if (t < NT - 1){
            float sink = 0.f;
            const float4* pp = (const float4*)(gbase0 + (size_t)(t + 1) * SLICE);
#pragma unroll
            for (int i = 0; i < 15; i++){ float4 v = pp[i * 256 + tid]; sink += v.x + v.w; }
            const float4* qq = (const float4*)(projb + (size_t)(t + 1) * LL * DD);
#pragma unroll
            for (int i = 0; i < 15; i++){ float4 v = qq[i * 256 + tid]; sink += v.x + v.w; }
            asm volatile("" :: "v"(sink));
        }
    }
}

// ---------------- MLP heads ----------------
__global__ __launch_bounds__(256) void mlp_kernel(
    const float* __restrict__ hseq,
    const float* __restrict__ sw1T, const float* __restrict__ sb1,
    const float* __restrict__ sw2,  const float* __restrict__ sb2,
    const float* __restrict__ sw3,  const float* __restrict__ sb3,
    const float* __restrict__ sw4,  const float* __restrict__ sb4,
    const float* __restrict__ vw1T, const float* __restrict__ vb1,
    const float* __restrict__ vw2,  const float* __restrict__ vb2,
    const float* __restrict__ vw3,  const float* __restrict__ vb3,
    const float* __restrict__ vw4,  const float* __restrict__ vb4,
    float* __restrict__ out)
{
    __shared__ float h0[HID];
    __shared__ float h1[2][100];
    __shared__ float h2[2][52];
    __shared__ float h3[2][12];
    int tb = blockIdx.x;
    int tid = threadIdx.x;
    for (int i = tid; i < HID; i += 256) h0[i] = hseq[(size_t)tb * HID + i];
    __syncthreads();
    if (tid < 100){
        float a = sb1[tid];
        for (int k = 0; k < HID; k++) a = fmaf(h0[k], sw1T[k*100 + tid], a);
        h1[0][tid] = fmaxf(a, 0.f);
    } else if (tid >= 128 && tid < 228){
        int u = tid - 128;
        float a = vb1[u];
        for (int k = 0; k < HID; k++) a = fmaf(h0[k], vw1T[k*100 + u], a);
        h1[1][u] = fmaxf(a, 0.f);
    }
    __syncthreads();
    if (tid < 50){
        float a = sb2[tid];
        for (int k = 0; k < 100; k++) a = fmaf(h1[0][k], sw2[tid*100 + k], a);
        h2[0][tid] = fmaxf(a, 0.f);
    } else if (tid >= 128 && tid < 178){
        int u = tid - 128;
        float a = vb2[u];
        for (int k = 0; k < 100; k++) a = fmaf(h1[1][k], vw2[u*100 + k], a);
        h2[1][u] = fmaxf(a, 0.f);
    }
    __syncthreads();
    if (tid < 10){
        float a = sb3[tid];
        for (int k = 0; k < 50; k++) a = fmaf(h2[0][k], sw3[tid*50 + k], a);
        h3[0][tid] = fmaxf(a, 0.f);
    } else if (tid >= 128 && tid < 138){
        int u = tid - 128;
        float a = vb3[u];
        for (int k = 0; k < 50; k++) a = fmaf(h2[1][k], vw3[u*50 + k], a);
        h3[1][u] = fmaxf(a, 0.f);
    }
    __syncthreads();
    if (tid == 0){
        float a = sb4[0];
        for (int k = 0; k < 10; k++) a = fmaf(h3[0][k], sw4[k], a);
        out[tb] = a;
    } else if (tid == 128){
        float a = vb4[0];
        for (int k = 0; k < 10; k++) a = fmaf(h3[1][k], vw4[k], a);
        out[360 + tb] = a;
    }
}

extern "C" void kernel_launch(void* const* d_in, const int* in_sizes, int n_in,
                              void* d_out, int out_size, void* d_ws, size_t ws_size,
                              hipStream_t stream)
{
    (void)in_sizes; (void)n_in; (void)out_size;
    if (ws_size < WS_NEEDED) return;

    const float* cam   = (const float*)d_in[0];
    const float* cw1   = (const float*)d_in[1];  const float* cb1 = (const float*)d_in[2];
    const float* cw2   = (const float*)d_in[3];  const float* cb2 = (const float*)d_in[4];
    const float* cw3   = (const float*)d_in[5];  const float* cb3 = (const float*)d_in[6];
    const float* cw4   = (const float*)d_in[7];  const float* cb4 = (const float*)d_in[8];
    const float* cw5   = (const float*)d_in[9];  const float* cb5 = (const float*)d_in[10];
    const float* pw    = (const float*)d_in[11]; const float* pb  = (const float*)d_in[12];
    const float* w_w   = (const float*)d_in[13]; const float* w_b = (const float*)d_in[14];
    const float* waw   = (const float*)d_in[15]; const float* wab = (const float*)d_in[16];
    const float* wih   = (const float*)d_in[17]; const float* whh = (const float*)d_in[18];
    const float* bih   = (const float*)d_in[19]; const float* bhh = (const float*)d_in[20];
    const float* sw1   = (const float*)d_in[21]; const float* sb1 = (const float*)d_in[22];
    const float* sw2   = (const float*)d_in[23]; const float* sb2 = (const float*)d_in[24];
    const float* sw3   = (const float*)d_in[25]; const float* sb3 = (const float*)d_in[26];
    const float* sw4   = (const float*)d_in[27]; const float* sb4 = (const float*)d_in[28];
    const float* vw1   = (const float*)d_in[29]; const float* vb1 = (const float*)d_in[30];
    const float* vw2   = (const float*)d_in[31]; const float* vb2 = (const float*)d_in[32];
    const float* vw3   = (const float*)d_in[33]; const float* vb3 = (const float*)d_in[34];
    const float* vw4   = (const float*)d_in[35]; const float* vb4 = (const float*)d_in[36];

    char* ws = (char*)d_ws;
    u16*   camcl = (u16*)(ws + CAMCL_OFF);
    u16*   a1    = (u16*)(ws + A1_OFF);
    u16*   a2    = (u16*)(ws + A2_OFF);
    u16*   a3    = (u16*)(ws + A3_OFF);
    u16*   a4    = (u16*)(ws + A4_OFF);
    u16*   a5    = (u16*)(ws + A5_OFF);
    u16*   w1b   = (u16*)(ws + W1B_OFF);
    u16*   w2b   = (u16*)(ws + W2B_OFF);
    u16*   w3b   = (u16*)(ws + W3B_OFF);
    u16*   w4b   = (u16*)(ws + W4B_OFF);
    u16*   w5b   = (u16*)(ws + W5B_OFF);
    float* feats = (float*)(ws + FEATS_OFF);
    float* proj  = (float*)(ws + PROJ_OFF);
    float* w_wT  = (float*)(ws + WWT_OFF);
    u16*   whh_p = (u16*)  (ws + WHHP_OFF);
    float* bsum  = (float*)(ws + BSUM_OFF);
    float* sw1T  = (float*)(ws + SW1T_OFF);
    float* vw1T  = (float*)(ws + VW1T_OFF);
    float* hx_g  = (float*)(ws + SC_HX);
    unsigned int* flg = (unsigned int*)(ws + SC_FLG);
    float* hseq  = (float*)(ws + HSEQ_OFF);
    u16*   G     = (u16*)  (ws + G_OFF);

    cam_to_cl<<<(NIMG*96*160 + 255)/256, 256, 0, stream>>>(cam, camcl);
    prep_wbf<<<64, 256, 0, stream>>>(cw1, w1b, 24,  3,  8, 5, 28, 32);
    prep_wbf<<<64, 256, 0, stream>>>(cw2, w2b, 36, 24, 24, 5, 28, 48);
    prep_wbf<<<64, 256, 0, stream>>>(cw3, w3b, 48, 36, 40, 5, 28, 48);
    prep_wbf<<<64, 256, 0, stream>>>(cw4, w4b, 64, 48, 48, 3, 10, 64);
    prep_wbf<<<64, 256, 0, stream>>>(cw5, w5b, 64, 64, 64, 3,  9, 64);

    conv_mfma<   8,    32,   24,  24,   5,  28,   2, 2, 96, 160, 48, 80,  8, 40>
        <<<dim3(12, NIMG), 256, 0, stream>>>(camcl, w1b, cb1, a1);
    conv_mfma<  24,    48,   36,  40,   5,  28,   2, 2, 48,  80, 24, 40,  8, 20>
        <<<dim3(6, NIMG), 256, 0, stream>>>(a1, w2b, cb2, a2);
    conv_mfma<  40,    48,   48,  48,   5,  28,   2, 2, 24,  40, 12, 20, 12, 20>
        <<<dim3(1, NIMG), 256, 0, stream>>>(a2, w3b, cb3, a3);
    conv_mfma<  48,    64,   64,  64,   3,  10,   1, 1, 12,  20, 12, 20, 12, 20>
        <<<dim3(1, NIMG), 256, 0, stream>>>(a3, w4b, cb4, a4);
    conv_mfma<  64,    64,   64,  64,   3,   9,   1, 1, 12,  20, 12, 20, 12, 20>
        <<<dim3(1, NIMG), 256, 0, stream>>>(a4, w5b, cb5, a5);

    extract_feats<<<(NIMG*12*20*64 + 255)/256, 256, 0, stream>>>(a5, feats);
    proj_kernel<<<NIMG*LL/4, 256, 0, stream>>>(feats, pw, pb, proj);
    prep<<<1024, 256, 0, stream>>>(w_w, whh, bih, bhh, w_wT, whh_p, bsum);
    gcompute_mfma2<<<dim3(8, 240), 256, 0, stream>>>(feats, wih, G);

    // zero scan state: hx parity buffers(16KB) + flags(512B)  (re-zeroed every replay)
    hipMemsetAsync(ws + SC_HX, 0, 16896, stream);

    scan_pc<<<TBLK, 256, 0, stream>>>(G, whh_p, bsum, proj, w_wT, w_b, waw, wab,
                                      hx_g, flg, hseq);

    prep2<<<256, 256, 0, stream>>>(sw1, vw1, sw1T, vw1T);

    mlp_kernel<<<360, 256, 0, stream>>>(hseq,
        sw1T, sb1, sw2, sb2, sw3, sb3, sw4, sb4,
        vw1T, vb1, vw2, vb2, vw3, vb3, vw4, vb4, (float*)d_out);
}

// Round 13
// 1636.083 us; speedup vs baseline: 1.1683x; 1.1398x over previous
//
#include <hip/hip_runtime.h>
#include <hip/hip_bf16.h>

typedef unsigned short u16;
using bf16x8 = __attribute__((ext_vector_type(8))) short;
using f32x4  = __attribute__((ext_vector_type(4))) float;

#define NB   4
#define NT   90
#define NIMG 360
#define LL   240
#define DD   64
#define HID  512
#define NJ   2048
#define GPB  16          // gates blocks per batch
#define TBLK (NB + NB*GPB) // 4 attn + 64 gates = 68

#define DEV __device__ __forceinline__

DEV float bf2f(u16 x){ unsigned int u = ((unsigned int)x) << 16; float f; __builtin_memcpy(&f, &u, 4); return f; }
DEV u16 f2bf(float f){ unsigned int u; __builtin_memcpy(&u, &f, 4); unsigned int r = (u + 0x7FFFu + ((u >> 16) & 1u)) >> 16; return (u16)r; }
DEV float sigm(float x){ return 1.f / (1.f + __expf(-x)); }
DEV float tanh_f(float x){ x = fminf(fmaxf(x, -15.f), 15.f); float e = __expf(2.f*x); return (e - 1.f) / (e + 1.f); }

// L3-coherent (agent-scope, relaxed) accessors for cross-XCD mutable state.
DEV void  ast(float* p, float v){ __hip_atomic_store(p, v, __ATOMIC_RELAXED, __HIP_MEMORY_SCOPE_AGENT); }
DEV float ald(const float* p){ return __hip_atomic_load(p, __ATOMIC_RELAXED, __HIP_MEMORY_SCOPE_AGENT); }
DEV void  astu(unsigned int* p, unsigned int v){ __hip_atomic_store(p, v, __ATOMIC_RELAXED, __HIP_MEMORY_SCOPE_AGENT); }
DEV unsigned int aldu(const unsigned int* p){ return __hip_atomic_load(p, __ATOMIC_RELAXED, __HIP_MEMORY_SCOPE_AGENT); }

// ---------------- workspace layout (bytes) ----------------
// G2 layout: [b][g(16)][t(90)][l(240)][128 jj] u16 — block (b,g) slice at step t is one
// contiguous 61,440B run.
static const size_t G_OFF     = 0;            // 353,894,400 B
static const size_t CAMCL_OFF = 0;            // conv temporaries alias over G
static const size_t A1_OFF    = 88473600;
static const size_t A2_OFF    = 154828800;
static const size_t A3_OFF    = 182476800;
static const size_t A4_OFF    = 190771200;
static const size_t A5_OFF    = 201830400;
static const size_t W1B_OFF   = 212889600;
static const size_t W2B_OFF   = 212903936;
static const size_t W3B_OFF   = 212968448;
static const size_t W4B_OFF   = 213075968;
static const size_t W5B_OFF   = 213137408;
static const size_t FEATS_OFF = 353894400;    // fp32 [360][240][64]; dead during scan
static const size_t SC_ALPHA  = 353894400;    // fp32 [4][240] (4KB slot)
static const size_t SC_HX     = 353898496;    // fp32 [2][4][512] = 16KB (parity double-buffer)
static const size_t SC_CTR    = 353914880;    // u32 [4][32] = 512B (per-batch arrival counters)
static const size_t SC_RDY    = 353915392;    // u32 [4] in one 128B line
static const size_t PROJ_OFF  = 376012800;    // fp32 [360][240][64]
static const size_t WWT_OFF   = 398131200;    // fp32 [512][64]   w_w^T
static const size_t WHHP_OFF  = 398262272;    // bf16 [512][2048] whh^T, j-permuted
static const size_t BSUM_OFF  = 400359424;    // fp32 [2048] bih+bhh, j-permuted
static const size_t SW1T_OFF  = 400367616;    // fp32 [512][100]
static const size_t VW1T_OFF  = 400572416;    // fp32 [512][100]
static const size_t HSEQ_OFF  = 400809984;    // fp32 [90][4][512]
static const size_t WS_NEEDED = 401547264;

// ---------------- camera NCHW fp32 -> channels-last bf16 [n][h][w][8] ----------------
__global__ __launch_bounds__(256) void cam_to_cl(const float* __restrict__ cam, u16* __restrict__ out)
{
    int i = blockIdx.x * 256 + threadIdx.x;
    if (i >= NIMG * 96 * 160) return;
    int hw = i % (96 * 160);
    int n  = i / (96 * 160);
    const float* p = cam + (size_t)n * 3 * 96 * 160 + hw;
    bf16x8 v;
    v[0] = (short)f2bf(p[0]);
    v[1] = (short)f2bf(p[15360]);
    v[2] = (short)f2bf(p[30720]);
    v[3] = 0; v[4] = 0; v[5] = 0; v[6] = 0; v[7] = 0;
    *(bf16x8*)&out[(size_t)i * 8] = v;
}

// ---------------- weight prep for convs ----------------
__global__ __launch_bounds__(256) void prep_wbf(
    const float* __restrict__ w, u16* __restrict__ wbf,
    int COUT, int CIN, int CI_PAD, int KHW, int CELLS_PAD, int M_PAD)
{
    int K_PAD = CELLS_PAD * CI_PAD;
    int total = M_PAD * K_PAD;
    for (int i = blockIdx.x * 256 + threadIdx.x; i < total; i += gridDim.x * 256){
        int co = i / K_PAD, kk = i % K_PAD;
        int cell = kk / CI_PAD, ci = kk % CI_PAD;
        float v = 0.f;
        if (co < COUT && cell < KHW * KHW && ci < CIN){
            int kh = cell / KHW, kw = cell % KHW;
            v = w[((size_t)(co * CIN + ci) * KHW + kh) * KHW + kw];
        }
        wbf[i] = f2bf(v);
    }
}

// ---------------- implicit-GEMM MFMA conv (channels-last bf16 in/out) ----------------
template<int CI_PAD, int M_PAD, int COUT, int CO_STORE, int KHW, int CELLS_PAD,
         int S, int P, int HIN, int WIN, int HOUT, int WOUT, int TOH, int TOW>
__global__ __launch_bounds__(256) void conv_mfma(
    const u16* __restrict__ in, const u16* __restrict__ wbf,
    const float* __restrict__ bias, u16* __restrict__ out)
{
    constexpr int K_PAD = CELLS_PAD * CI_PAD;
    constexpr int CP8   = CI_PAD / 8;
    constexpr int TIH   = (TOH - 1) * S + KHW;
    constexpr int TIW   = (TOW - 1) * S + KHW;
    constexpr int TIW_H = (TIW + 1) / 2;
    constexpr int NF    = TOH * TOW / 16;
    constexpr int NK0   = K_PAD / 32;
    constexpr int MF    = M_PAD / 16;
    constexpr int NPW   = (NF + 3) / 4;
    constexpr int LDSE  = (S == 2) ? TIH * CP8 * 2 * TIW_H * 8 : TIH * CP8 * TIW * 8;
    static_assert((TOH * TOW) % 16 == 0, "N tile");
    static_assert(K_PAD % 32 == 0, "K pad");

    __shared__ u16 lds[LDSE];

    int tile = blockIdx.x, n = blockIdx.y;
    constexpr int TW_T = WOUT / TOW;
    int th = tile / TW_T, tw = tile % TW_T;
    int oh0 = th * TOH, ow0 = tw * TOW;
    int ih0 = oh0 * S - P, iw0 = ow0 * S - P;
    int tid = threadIdx.x;

    constexpr int CHUNKS = TIH * TIW * CP8;
    for (int i = tid; i < CHUNKS; i += 256){
        int c8 = i % CP8; int r2 = i / CP8;
        int iw = r2 % TIW, ih = r2 / TIW;
        int ihg = ih0 + ih, iwg = iw0 + iw;
        bf16x8 v = {0,0,0,0,0,0,0,0};
        if (ihg >= 0 && ihg < HIN && iwg >= 0 && iwg < WIN)
            v = *(const bf16x8*)&in[(((size_t)n * HIN + ihg) * WIN + iwg) * CI_PAD + c8 * 8];
        int off;
        if (S == 2) off = (((ih * CP8 + c8) * 2 + (iw & 1)) * TIW_H + (iw >> 1)) * 8;
        else        off = ((ih * CP8 + c8) * TIW + iw) * 8;
        *(bf16x8*)&lds[off] = v;
    }
    __syncthreads();

    int lane = tid & 63, wv = tid >> 6;
    int col = lane & 15, grp = lane >> 4;

    int ihb[NPW], iwb[NPW];
    bool act[NPW];
#pragma unroll
    for (int i2 = 0; i2 < NPW; i2++){
        int nf = wv + i2 * 4;
        act[i2] = (nf < NF);
        int nfc = act[i2] ? nf : 0;
        int nsp = nfc * 16 + col;
        ihb[i2] = (nsp / TOW) * S;
        iwb[i2] = (nsp % TOW) * S;
    }

    f32x4 acc[MF][NPW];
#pragma unroll
    for (int mf = 0; mf < MF; mf++)
#pragma unroll
        for (int i2 = 0; i2 < NPW; i2++)
            acc[mf][i2] = (f32x4){0.f, 0.f, 0.f, 0.f};

    for (int k0 = 0; k0 < NK0; k0++){
        bf16x8 a[MF];
#pragma unroll
        for (int mf = 0; mf < MF; mf++)
            a[mf] = *(const bf16x8*)&wbf[(size_t)(mf * 16 + col) * K_PAD + k0 * 32 + grp * 8];
        int k8 = k0 * 32 + grp * 8;
        int cell = k8 / CI_PAD;
        int ci0  = k8 - cell * CI_PAD;
        if (cell >= KHW * KHW) cell = 0;
        int kh = cell / KHW, kw = cell - (cell / KHW) * KHW;
        int cb = ci0 >> 3;
#pragma unroll
        for (int i2 = 0; i2 < NPW; i2++){
            if (!act[i2]) continue;
            int ih = ihb[i2] + kh;
            int off;
            if (S == 2) off = (((ih * CP8 + cb) * 2 + (kw & 1)) * TIW_H + (iwb[i2] >> 1) + (kw >> 1)) * 8;
            else        off = ((ih * CP8 + cb) * TIW + iwb[i2] + kw) * 8;
            bf16x8 b = *(const bf16x8*)&lds[off];
#pragma unroll
            for (int mf = 0; mf < MF; mf++)
                acc[mf][i2] = __builtin_amdgcn_mfma_f32_16x16x32_bf16(a[mf], b, acc[mf][i2], 0, 0, 0);
        }
    }

#pragma unroll
    for (int i2 = 0; i2 < NPW; i2++){
        if (!act[i2]) continue;
        int nf = wv + i2 * 4;
        int nsp = nf * 16 + col;
        int oh = oh0 + nsp / TOW, ow = ow0 + nsp % TOW;
        size_t obase = (((size_t)n * HOUT + oh) * WOUT + ow) * CO_STORE;
#pragma unroll
        for (int mf = 0; mf < MF; mf++){
            int cobase = mf * 16 + grp * 4;
#pragma unroll
            for (int r = 0; r < 4; r++){
                int co = cobase + r;
                if (co < CO_STORE){
                    float x = (co < COUT) ? fmaxf(acc[mf][i2][r] + bias[co], 0.f) : 0.f;
                    out[obase + co] = f2bf(x);
                }
            }
        }
    }
}

// ---------------- feats rearrange ----------------
__global__ __launch_bounds__(256) void extract_feats(const u16* __restrict__ a5, float* __restrict__ feats)
{
    int idx = blockIdx.x * 256 + threadIdx.x;
    if (idx >= NIMG * 12 * 20 * 64) return;
    int c = idx & 63; int t1 = idx >> 6;
    int w = t1 % 20; t1 /= 20;
    int h = t1 % 12; int n = t1 / 12;
    float v = bf2f(a5[idx]);
    int flat = w * 768 + c * 12 + h;
    int d = flat / 240, l = flat % 240;
    feats[((size_t)n * LL + l) * DD + d] = v;
}

// ---------------- proj = feats @ proj_w.T + proj_b ----------------
__global__ __launch_bounds__(256) void proj_kernel(
    const float* __restrict__ feats, const float* __restrict__ pw,
    const float* __restrict__ pb, float* __restrict__ proj)
{
    __shared__ float pws[64][65];
    __shared__ float fs[4][64];
    int tid = threadIdx.x;
    size_t R0 = (size_t)blockIdx.x * 4;
    for (int i = tid; i < 4096; i += 256){
        int dd = i / 64, d = i % 64;
        pws[d][dd] = pw[dd*64 + d];
    }
    { int r = tid / 64, d = tid % 64; fs[r][d] = feats[(R0 + r)*64 + d]; }
    __syncthreads();
    int r = tid / 64, dd = tid % 64;
    float a = pb[dd];
    for (int d = 0; d < 64; d++) a = fmaf(fs[r][d], pws[d][dd], a);
    proj[(R0 + r)*64 + dd] = a;
}

// ---------------- prep: whh permute, bias combine, w_w transpose ----------------
__global__ __launch_bounds__(256) void prep(
    const float* __restrict__ w_w, const float* __restrict__ whh,
    const float* __restrict__ bih, const float* __restrict__ bhh,
    float* __restrict__ w_wT, u16* __restrict__ whh_p, float* __restrict__ bsum)
{
    int idx = blockIdx.x * 256 + threadIdx.x;
    int stride = gridDim.x * 256;
    for (int i = idx; i < 512*64; i += stride){
        int k = i / 64, dd = i % 64;
        w_wT[i] = w_w[dd*512 + k];
    }
    for (int i = idx; i < 512*2048; i += stride){
        int k = i / 2048, jj = i % 2048;
        int u = jj >> 2, g = jj & 3, j = g*512 + u;
        whh_p[i] = f2bf(whh[(size_t)j*512 + k]);
    }
    for (int i = idx; i < 2048; i += stride){
        int u = i >> 2, g = i & 3, j = g*512 + u;
        bsum[i] = bih[j] + bhh[j];
    }
}

// ---------------- prep2: MLP first-layer transposes ----------------
__global__ __launch_bounds__(256) void prep2(
    const float* __restrict__ sw1, const float* __restrict__ vw1,
    float* __restrict__ sw1T, float* __restrict__ vw1T)
{
    int idx = blockIdx.x * 256 + threadIdx.x;
    int stride = gridDim.x * 256;
    for (int i = idx; i < 512*100; i += stride){
        int k = i / 100, u = i % 100;
        sw1T[i] = sw1[u*512 + k];
        vw1T[i] = vw1[u*512 + k];
    }
}

// ---------------- gcompute via MFMA; G2 slice-contiguous layout ----------------
__global__ __launch_bounds__(256, 2) void gcompute_mfma2(
    const float* __restrict__ feats, const float* __restrict__ wih, u16* __restrict__ G)
{
    __shared__ u16 Bsw[256 * 64];
    __shared__ u16 Asw[128 * 64];
    float (*obuf)[1024] = (float(*)[1024])Asw;

    int jt = blockIdx.x, l = blockIdx.y;
    int j0 = jt * 256;
    int tid = threadIdx.x;
    int g8 = tid & 7;

    for (int p = 0; p < 8; p++){
        int row = p * 32 + (tid >> 3);
        int jj = j0 + row;
        int j = (jj & 3) * 512 + (jj >> 2);
        const float* src = wih + (size_t)j * 15360 + l * 64 + g8 * 8;
        float4 v0 = *(const float4*)src;
        float4 v1 = *(const float4*)(src + 4);
        bf16x8 pk;
        pk[0]=(short)f2bf(v0.x); pk[1]=(short)f2bf(v0.y); pk[2]=(short)f2bf(v0.z); pk[3]=(short)f2bf(v0.w);
        pk[4]=(short)f2bf(v1.x); pk[5]=(short)f2bf(v1.y); pk[6]=(short)f2bf(v1.z); pk[7]=(short)f2bf(v1.w);
        *(bf16x8*)&Bsw[(row * 8 + (g8 ^ (row & 7))) * 8] = pk;
    }
    __syncthreads();

    int lane = tid & 63, w = tid >> 6;
    int col = lane & 15, grp = lane >> 4;

    bf16x8 bfr[2][4];
#pragma unroll
    for (int k0 = 0; k0 < 2; k0++)
#pragma unroll
        for (int nf = 0; nf < 4; nf++){
            int row = w * 64 + nf * 16 + col;
            bfr[k0][nf] = *(const bf16x8*)&Bsw[(row * 8 + ((k0 * 4 + grp) ^ (row & 7))) * 8];
        }

    for (int mt = 0; mt < 3; mt++){
        int m0 = mt * 128;
        __syncthreads();
        for (int p = 0; p < 4; p++){
            int row = p * 32 + (tid >> 3);
            const float* src = feats + ((size_t)(m0 + row) * LL + l) * DD + g8 * 8;
            float4 v0 = *(const float4*)src;
            float4 v1 = *(const float4*)(src + 4);
            bf16x8 pk;
            pk[0]=(short)f2bf(v0.x); pk[1]=(short)f2bf(v0.y); pk[2]=(short)f2bf(v0.z); pk[3]=(short)f2bf(v0.w);
            pk[4]=(short)f2bf(v1.x); pk[5]=(short)f2bf(v1.y); pk[6]=(short)f2bf(v1.z); pk[7]=(short)f2bf(v1.w);
            *(bf16x8*)&Asw[(row * 8 + (g8 ^ (row & 7))) * 8] = pk;
        }
        __syncthreads();

        f32x4 acc[8][4];
#pragma unroll
        for (int mf = 0; mf < 8; mf++)
#pragma unroll
            for (int nf = 0; nf < 4; nf++) acc[mf][nf] = (f32x4){0.f,0.f,0.f,0.f};

#pragma unroll
        for (int k0 = 0; k0 < 2; k0++){
#pragma unroll
            for (int mf = 0; mf < 8; mf++){
                int row = mf * 16 + col;
                bf16x8 a = *(const bf16x8*)&Asw[(row * 8 + ((k0 * 4 + grp) ^ (row & 7))) * 8];
#pragma unroll
                for (int nf = 0; nf < 4; nf++)
                    acc[mf][nf] = __builtin_amdgcn_mfma_f32_16x16x32_bf16(a, bfr[k0][nf], acc[mf][nf], 0, 0, 0);
            }
        }
        __syncthreads();

#pragma unroll
        for (int mf = 0; mf < 8; mf++){
#pragma unroll
            for (int nf = 0; nf < 4; nf++)
#pragma unroll
                for (int r = 0; r < 4; r++)
                    obuf[w][(grp * 4 + r) * 64 + nf * 16 + col] = acc[mf][nf][r];
#pragma unroll
            for (int p = 0; p < 2; p++){
                int rloc = p * 8 + (lane >> 3);
                int c0 = (lane & 7) * 8;
                float4 r0 = *(const float4*)&obuf[w][rloc * 64 + c0];
                float4 r1 = *(const float4*)&obuf[w][rloc * 64 + c0 + 4];
                int m = m0 + mf * 16 + rloc;
                if (m < NIMG){
                    int b = m / NT, tt = m % NT;
                    int jj8 = j0 + w * 64 + c0;
                    int gg2 = jj8 >> 7, jjl = jj8 & 127;
                    bf16x8 pk;
                    pk[0]=(short)f2bf(r0.x); pk[1]=(short)f2bf(r0.y); pk[2]=(short)f2bf(r0.z); pk[3]=(short)f2bf(r0.w);
                    pk[4]=(short)f2bf(r1.x); pk[5]=(short)f2bf(r1.y); pk[6]=(short)f2bf(r1.z); pk[7]=(short)f2bf(r1.w);
                    *(bf16x8*)&G[(((size_t)(b * GPB + gg2) * NT + tt) * LL + l) * 128 + jjl] = pk;
                }
            }
        }
    }
}

// ---------------- persistent batch-partitioned scan (4 x [1 attn + 16 gates]) ----------------
// R10 structure with wave-split latency hiding:
//  - attn block: proj(t+1) staged TRANSPOSED by waves 1-3 while wave 0 polls ctr.
//  - gates block: G(t+1) prefetched by waves 1-3 with sink consumed next iteration;
//    their vmcnt drains at the rdy barrier, overlapping wave 0's poll.
__global__ __launch_bounds__(256) void scan_pc(
    const u16* __restrict__ G, const u16* __restrict__ whh_p,
    const float* __restrict__ bsum, const float* __restrict__ proj,
    const float* __restrict__ w_wT, const float* __restrict__ w_b,
    const float* __restrict__ waw, const float* __restrict__ wab,
    float* __restrict__ alpha_g, float* __restrict__ hx_g,
    unsigned int* __restrict__ ctr, unsigned int* __restrict__ rdy,
    float* __restrict__ hseq)
{
    int tid = threadIdx.x, blk = blockIdx.x;

    if (blk < NB){
        // ================= ATTN BLOCK (batch b) =================
        __shared__ float projT[DD * 241];  // 61.7KB transposed proj: [d][l]
        __shared__ float hloc[HID];        // 2KB
        __shared__ float apjs[DD];         // 256B
        __shared__ float scr[256];         // 1KB (gemv partials / es values)
        int b = blk;
        float wb0 = wab[0];

        // init: stage proj(0) transposed (all threads), alpha(0) with hx=0, rdy=1
        {
            const float* src = proj + ((size_t)(b * NT + 0)) * LL * DD;
            for (int it = 0; it < 15; it++){
                int i4 = it * 256 + tid;
                int l = i4 >> 4, d0 = (i4 & 15) * 4;
                float4 v = *(const float4*)&src[l * 64 + d0];
                projT[(d0 + 0) * 241 + l] = v.x;
                projT[(d0 + 1) * 241 + l] = v.y;
                projT[(d0 + 2) * 241 + l] = v.z;
                projT[(d0 + 3) * 241 + l] = v.w;
            }
        }
        if (tid < DD) apjs[tid] = w_b[tid];
        __syncthreads();
        if (tid < LL){
            float e = 0.f;
#pragma unroll
            for (int d = 0; d < DD; d++)
                e = fmaf(tanh_f(projT[d * 241 + tid] + apjs[d]), waw[d], e);
            scr[tid] = e + wb0;
        }
        __syncthreads();
        if (tid < 64){
            float m = -1e30f;
            for (int l = tid; l < LL; l += 64) m = fmaxf(m, scr[l]);
#pragma unroll
            for (int off = 32; off; off >>= 1) m = fmaxf(m, __shfl_xor(m, off));
            float ex[4]; int c = 0; float ssum = 0.f;
            for (int l = tid; l < LL; l += 64){ float e2 = __expf(scr[l] - m); ex[c++] = e2; ssum += e2; }
#pragma unroll
            for (int off = 32; off; off >>= 1) ssum += __shfl_xor(ssum, off);
            float inv = 1.f / ssum; c = 0;
            for (int l = tid; l < LL; l += 64) ast(&alpha_g[b * LL + l], ex[c++] * inv);
        }
        __syncthreads();
        if (tid == 0) astu(&rdy[b], 1u);

        for (int t = 0; t < NT - 1; t++){
            // waves 1-3 stage proj(t+1) transposed; wave 0 polls ctr concurrently
            if (tid >= 64){
                int idx = tid - 64;
                const float* src = proj + ((size_t)(b * NT + t + 1)) * LL * DD;
#pragma unroll
                for (int it = 0; it < 20; it++){
                    int i4 = it * 192 + idx;
                    int l = i4 >> 4, d0 = (i4 & 15) * 4;
                    float4 v = *(const float4*)&src[l * 64 + d0];
                    projT[(d0 + 0) * 241 + l] = v.x;
                    projT[(d0 + 1) * 241 + l] = v.y;
                    projT[(d0 + 2) * 241 + l] = v.z;
                    projT[(d0 + 3) * 241 + l] = v.w;
                }
            } else if (tid == 0){
                unsigned int tgt = 16u * (t + 1);
                int g = 0;
                while (aldu(&ctr[b * 32]) < tgt){
                    if (++g > (1 << 24)) break;
                    __builtin_amdgcn_s_sleep(1);
                }
            }
            __syncthreads();

            // stage h(t) from parity buffer
            {
                const float* hsrc = hx_g + (size_t)((t + 1) & 1) * (NB * HID) + b * HID;
                hloc[tid] = ald(&hsrc[tid]);
                hloc[tid + 256] = ald(&hsrc[tid + 256]);
            }
            __syncthreads();

            // apj gemv (4-way k split)
            {
                int dd = tid & 63, dq = tid >> 6;
                float p = 0.f;
                for (int ki = 0; ki < 128; ki++){
                    int k = dq * 128 + ki;
                    p = fmaf(hloc[k], w_wT[k * 64 + dd], p);
                }
                scr[dq * 64 + dd] = p;
            }
            __syncthreads();
            if (tid < 64) apjs[tid] = w_b[tid] + scr[tid] + scr[64 + tid] + scr[128 + tid] + scr[192 + tid];
            __syncthreads();
            // es (conflict-free projT reads) + softmax
            float ev = 0.f;
            if (tid < LL){
#pragma unroll
                for (int d = 0; d < DD; d++)
                    ev = fmaf(tanh_f(projT[d * 241 + tid] + apjs[d]), waw[d], ev);
                ev += wb0;
            }
            __syncthreads();
            if (tid < LL) scr[tid] = ev;
            __syncthreads();
            if (tid < 64){
                float m = -1e30f;
                for (int l = tid; l < LL; l += 64) m = fmaxf(m, scr[l]);
#pragma unroll
                for (int off = 32; off; off >>= 1) m = fmaxf(m, __shfl_xor(m, off));
                float ex[4]; int c = 0; float ssum = 0.f;
                for (int l = tid; l < LL; l += 64){ float e2 = __expf(scr[l] - m); ex[c++] = e2; ssum += e2; }
#pragma unroll
                for (int off = 32; off; off >>= 1) ssum += __shfl_xor(ssum, off);
                float inv = 1.f / ssum; c = 0;
                for (int l = tid; l < LL; l += 64) ast(&alpha_g[b * LL + l], ex[c++] * inv);
            }
            __syncthreads();
            if (tid == 0) astu(&rdy[b], (unsigned int)(t + 2));
        }
    } else {
        // ================= GATES BLOCK (batch b, group g) =================
        __shared__ float als[LL];        // 960B
        __shared__ float hxs[HID];       // 2KB
        __shared__ float red[8][128];    // 4KB
        __shared__ float gat[128];       // 512B
        __shared__ float cxl[32];        // 128B
        int idx = blk - NB;
        int b = idx & 3, g = idx >> 2;
        int jq = tid & 31, lg = tid >> 5;       // 32 jj-quads x 8 l/k-groups
        const size_t SLICE = (size_t)LL * 128;
        const u16* gbase0 = G + ((size_t)(b * GPB + g) * NT) * SLICE;

        if (tid < 32) cxl[tid] = 0.f;

        float sink = 0.f;
        // initial prefetch G(0) on waves 1-3 (consumed at first loop top)
        if (tid >= 64){
            int pidx = tid - 64;
            const float4* pp = (const float4*)(gbase0);
            float s2 = 0.f;
#pragma unroll
            for (int i = 0; i < 20; i++){ float4 v = pp[i * 192 + pidx]; s2 += v.x + v.w; }
            sink = s2;
        }

        for (int t = 0; t < NT; t++){
            // wait alpha(t) ready; waves 1-3 drain their prefetch at the barrier meanwhile
            if (tid == 0){
                int gu = 0;
                while (aldu(&rdy[b]) < (unsigned int)(t + 1)){
                    if (++gu > (1 << 24)) break;
                    __builtin_amdgcn_s_sleep(1);
                }
            }
            __syncthreads();
            asm volatile("" :: "v"(sink));   // consume previous prefetch (already complete)

            // stage alpha(t) + h(t-1)
            if (tid < LL) als[tid] = ald(&alpha_g[b * LL + tid]);
            {
                const float* hsrc = hx_g + (size_t)(t & 1) * (NB * HID) + b * HID;
                hxs[tid] = ald(&hsrc[tid]);
                hxs[tid + 256] = ald(&hsrc[tid + 256]);
            }
            __syncthreads();

            // gates partial: sum_l alpha*G (30 l, L2-hot contiguous) + sum_k hx*whh (64 k)
            float ac0 = 0.f, ac1 = 0.f, ac2 = 0.f, ac3 = 0.f;
            {
                const u16* gp = gbase0 + (size_t)t * SLICE + (size_t)(lg * 30) * 128 + jq * 4;
#pragma unroll 6
                for (int i = 0; i < 30; i++){
                    short4 gv = *(const short4*)(gp + i * 128);
                    float al = als[lg * 30 + i];
                    ac0 = fmaf(al, bf2f((u16)gv.x), ac0);
                    ac1 = fmaf(al, bf2f((u16)gv.y), ac1);
                    ac2 = fmaf(al, bf2f((u16)gv.z), ac2);
                    ac3 = fmaf(al, bf2f((u16)gv.w), ac3);
                }
                const u16* wp = whh_p + (size_t)(lg * 64) * NJ + g * 128 + jq * 4;
#pragma unroll 8
                for (int ki = 0; ki < 64; ki++){
                    short4 wv = *(const short4*)(wp + (size_t)ki * NJ);
                    float h = hxs[lg * 64 + ki];
                    ac0 = fmaf(h, bf2f((u16)wv.x), ac0);
                    ac1 = fmaf(h, bf2f((u16)wv.y), ac1);
                    ac2 = fmaf(h, bf2f((u16)wv.z), ac2);
                    ac3 = fmaf(h, bf2f((u16)wv.w), ac3);
                }
            }
            red[lg][jq * 4 + 0] = ac0;
            red[lg][jq * 4 + 1] = ac1;
            red[lg][jq * 4 + 2] = ac2;
            red[lg][jq * 4 + 3] = ac3;
            __syncthreads();
            if (tid < 128){
                float v = 0.f;
#pragma unroll
                for (int q = 0; q < 8; q++) v += red[q][tid];
                gat[tid] = v;
            }
            __syncthreads();

            // local pointwise cell for units [g*32, g*32+32)
            if (tid < 32){
                int jjb = g * 128 + tid * 4;
                float4 bs = *(const float4*)&bsum[jjb];
                float gi = gat[tid*4 + 0] + bs.x;
                float gf = gat[tid*4 + 1] + bs.y;
                float gg = gat[tid*4 + 2] + bs.z;
                float go = gat[tid*4 + 3] + bs.w;
                float c = sigm(gf) * cxl[tid] + sigm(gi) * tanhf(gg);
                cxl[tid] = c;
                float h = sigm(go) * tanhf(c);
                int u = g * 32 + tid;
                ast(&hx_g[(size_t)((t + 1) & 1) * (NB * HID) + b * HID + u], h);
                hseq[((size_t)t * NB + b) * HID + u] = h;
            }
            __syncthreads();          // drains h stores (vmcnt 0 before barrier)
            if (tid == 0)
                __hip_atomic_fetch_add(&ctr[b * 32], 1u, __ATOMIC_RELAXED, __HIP_MEMORY_SCOPE_AGENT);

            // prefetch G(t+1) on waves 1-3 ONLY; no immediate consume — drains at next barrier
            if (t < NT - 1 && tid >= 64){
                int pidx = tid - 64;
                const float4* pp = (const float4*)(gbase0 + (size_t)(t + 1) * SLICE);
                float s2 = 0.f;
#pragma unroll
                for (int i = 0; i < 20; i++){ float4 v = pp[i * 192 + pidx]; s2 += v.x + v.w; }
                sink = s2;
            }
        }
    }
}

// ---------------- MLP heads ----------------
__global__ __launch_bounds__(256) void mlp_kernel(
    const float* __restrict__ hseq,
    const float* __restrict__ sw1T, const float* __restrict__ sb1,
    const float* __restrict__ sw2,  const float* __restrict__ sb2,
    const float* __restrict__ sw3,  const float* __restrict__ sb3,
    const float* __restrict__ sw4,  const float* __restrict__ sb4,
    const float* __restrict__ vw1T, const float* __restrict__ vb1,
    const float* __restrict__ vw2,  const float* __restrict__ vb2,
    const float* __restrict__ vw3,  const float* __restrict__ vb3,
    const float* __restrict__ vw4,  const float* __restrict__ vb4,
    float* __restrict__ out)
{
    __shared__ float h0[HID];
    __shared__ float h1[2][100];
    __shared__ float h2[2][52];
    __shared__ float h3[2][12];
    int tb = blockIdx.x;
    int tid = threadIdx.x;
    for (int i = tid; i < HID; i += 256) h0[i] = hseq[(size_t)tb * HID + i];
    __syncthreads();
    if (tid < 100){
        float a = sb1[tid];
        for (int k = 0; k < HID; k++) a = fmaf(h0[k], sw1T[k*100 + tid], a);
        h1[0][tid] = fmaxf(a, 0.f);
    } else if (tid >= 128 && tid < 228){
        int u = tid - 128;
        float a = vb1[u];
        for (int k = 0; k < HID; k++) a = fmaf(h0[k], vw1T[k*100 + u], a);
        h1[1][u] = fmaxf(a, 0.f);
    }
    __syncthreads();
    if (tid < 50){
        float a = sb2[tid];
        for (int k = 0; k < 100; k++) a = fmaf(h1[0][k], sw2[tid*100 + k], a);
        h2[0][tid] = fmaxf(a, 0.f);
    } else if (tid >= 128 && tid < 178){
        int u = tid - 128;
        float a = vb2[u];
        for (int k = 0; k < 100; k++) a = fmaf(h1[1][k], vw2[u*100 + k], a);
        h2[1][u] = fmaxf(a, 0.f);
    }
    __syncthreads();
    if (tid < 10){
        float a = sb3[tid];
        for (int k = 0; k < 50; k++) a = fmaf(h2[0][k], sw3[tid*50 + k], a);
        h3[0][tid] = fmaxf(a, 0.f);
    } else if (tid >= 128 && tid < 138){
        int u = tid - 128;
        float a = vb3[u];
        for (int k = 0; k < 50; k++) a = fmaf(h2[1][k], vw3[u*50 + k], a);
        h3[1][u] = fmaxf(a, 0.f);
    }
    __syncthreads();
    if (tid == 0){
        float a = sb4[0];
        for (int k = 0; k < 10; k++) a = fmaf(h3[0][k], sw4[k], a);
        out[tb] = a;
    } else if (tid == 128){
        float a = vb4[0];
        for (int k = 0; k < 10; k++) a = fmaf(h3[1][k], vw4[k], a);
        out[360 + tb] = a;
    }
}

extern "C" void kernel_launch(void* const* d_in, const int* in_sizes, int n_in,
                              void* d_out, int out_size, void* d_ws, size_t ws_size,
                              hipStream_t stream)
{
    (void)in_sizes; (void)n_in; (void)out_size;
    if (ws_size < WS_NEEDED) return;

    const float* cam   = (const float*)d_in[0];
    const float* cw1   = (const float*)d_in[1];  const float* cb1 = (const float*)d_in[2];
    const float* cw2   = (const float*)d_in[3];  const float* cb2 = (const float*)d_in[4];
    const float* cw3   = (const float*)d_in[5];  const float* cb3 = (const float*)d_in[6];
    const float* cw4   = (const float*)d_in[7];  const float* cb4 = (const float*)d_in[8];
    const float* cw5   = (const float*)d_in[9];  const float* cb5 = (const float*)d_in[10];
    const float* pw    = (const float*)d_in[11]; const float* pb  = (const float*)d_in[12];
    const float* w_w   = (const float*)d_in[13]; const float* w_b = (const float*)d_in[14];
    const float* waw   = (const float*)d_in[15]; const float* wab = (const float*)d_in[16];
    const float* wih   = (const float*)d_in[17]; const float* whh = (const float*)d_in[18];
    const float* bih   = (const float*)d_in[19]; const float* bhh = (const float*)d_in[20];
    const float* sw1   = (const float*)d_in[21]; const float* sb1 = (const float*)d_in[22];
    const float* sw2   = (const float*)d_in[23]; const float* sb2 = (const float*)d_in[24];
    const float* sw3   = (const float*)d_in[25]; const float* sb3 = (const float*)d_in[26];
    const float* sw4   = (const float*)d_in[27]; const float* sb4 = (const float*)d_in[28];
    const float* vw1   = (const float*)d_in[29]; const float* vb1 = (const float*)d_in[30];
    const float* vw2   = (const float*)d_in[31]; const float* vb2 = (const float*)d_in[32];
    const float* vw3   = (const float*)d_in[33]; const float* vb3 = (const float*)d_in[34];
    const float* vw4   = (const float*)d_in[35]; const float* vb4 = (const float*)d_in[36];

    char* ws = (char*)d_ws;
    u16*   camcl = (u16*)(ws + CAMCL_OFF);
    u16*   a1    = (u16*)(ws + A1_OFF);
    u16*   a2    = (u16*)(ws + A2_OFF);
    u16*   a3    = (u16*)(ws + A3_OFF);
    u16*   a4    = (u16*)(ws + A4_OFF);
    u16*   a5    = (u16*)(ws + A5_OFF);
    u16*   w1b   = (u16*)(ws + W1B_OFF);
    u16*   w2b   = (u16*)(ws + W2B_OFF);
    u16*   w3b   = (u16*)(ws + W3B_OFF);
    u16*   w4b   = (u16*)(ws + W4B_OFF);
    u16*   w5b   = (u16*)(ws + W5B_OFF);
    float* feats = (float*)(ws + FEATS_OFF);
    float* proj  = (float*)(ws + PROJ_OFF);
    float* w_wT  = (float*)(ws + WWT_OFF);
    u16*   whh_p = (u16*)  (ws + WHHP_OFF);
    float* bsum  = (float*)(ws + BSUM_OFF);
    float* sw1T  = (float*)(ws + SW1T_OFF);
    float* vw1T  = (float*)(ws + VW1T_OFF);
    float* alpha = (float*)(ws + SC_ALPHA);
    float* hx_g  = (float*)(ws + SC_HX);
    unsigned int* ctr = (unsigned int*)(ws + SC_CTR);
    unsigned int* rdy = (unsigned int*)(ws + SC_RDY);
    float* hseq  = (float*)(ws + HSEQ_OFF);
    u16*   G     = (u16*)  (ws + G_OFF);

    cam_to_cl<<<(NIMG*96*160 + 255)/256, 256, 0, stream>>>(cam, camcl);
    prep_wbf<<<64, 256, 0, stream>>>(cw1, w1b, 24,  3,  8, 5, 28, 32);
    prep_wbf<<<64, 256, 0, stream>>>(cw2, w2b, 36, 24, 24, 5, 28, 48);
    prep_wbf<<<64, 256, 0, stream>>>(cw3, w3b, 48, 36, 40, 5, 28, 48);
    prep_wbf<<<64, 256, 0, stream>>>(cw4, w4b, 64, 48, 48, 3, 10, 64);
    prep_wbf<<<64, 256, 0, stream>>>(cw5, w5b, 64, 64, 64, 3,  9, 64);

    conv_mfma<   8,    32,   24,  24,   5,  28,   2, 2, 96, 160, 48, 80,  8, 40>
        <<<dim3(12, NIMG), 256, 0, stream>>>(camcl, w1b, cb1, a1);
    conv_mfma<  24,    48,   36,  40,   5,  28,   2, 2, 48,  80, 24, 40,  8, 20>
        <<<dim3(6, NIMG), 256, 0, stream>>>(a1, w2b, cb2, a2);
    conv_mfma<  40,    48,   48,  48,   5,  28,   2, 2, 24,  40, 12, 20, 12, 20>
        <<<dim3(1, NIMG), 256, 0, stream>>>(a2, w3b, cb3, a3);
    conv_mfma<  48,    64,   64,  64,   3,  10,   1, 1, 12,  20, 12, 20, 12, 20>
        <<<dim3(1, NIMG), 256, 0, stream>>>(a3, w4b, cb4, a4);
    conv_mfma<  64,    64,   64,  64,   3,   9,   1, 1, 12,  20, 12, 20, 12, 20>
        <<<dim3(1, NIMG), 256, 0, stream>>>(a4, w5b, cb5, a5);

    extract_feats<<<(NIMG*12*20*64 + 255)/256, 256, 0, stream>>>(a5, feats);
    proj_kernel<<<NIMG*LL/4, 256, 0, stream>>>(feats, pw, pb, proj);
    prep<<<1024, 256, 0, stream>>>(w_w, whh, bih, bhh, w_wT, whh_p, bsum);
    gcompute_mfma2<<<dim3(8, 240), 256, 0, stream>>>(feats, wih, G);

    // zero scan state: alpha(4KB) + hx parity buffers(16KB) + ctr(512B) + rdy(128B)
    hipMemsetAsync(ws + SC_ALPHA, 0, 21120, stream);

    scan_pc<<<TBLK, 256, 0, stream>>>(G, whh_p, bsum, proj, w_wT, w_b, waw, wab,
                                      alpha, hx_g, ctr, rdy, hseq);

    prep2<<<256, 256, 0, stream>>>(sw1, vw1, sw1T, vw1T);

    mlp_kernel<<<360, 256, 0, stream>>>(hseq,
        sw1T, sb1, sw2, sb2, sw3, sb3, sw4, sb4,
        vw1T, vb1, vw2, vb2, vw3, vb3, vw4, vb4, (float*)d_out);
}

// Round 14
// 1421.889 us; speedup vs baseline: 1.3443x; 1.1506x over previous
//
#include <hip/hip_runtime.h>
#include <hip/hip_bf16.h>

typedef unsigned short u16;
using bf16x8 = __attribute__((ext_vector_type(8))) short;
using f32x4  = __attribute__((ext_vector_type(4))) float;

#define NB   4
#define NT   90
#define NIMG 360
#define LL   240
#define DD   64
#define HID  512
#define NJ   2048
#define GPB  16          // gates blocks per batch
#define TBLK (NB + NB*GPB) // 4 attn + 64 gates = 68

#define DEV __device__ __forceinline__

DEV float bf2f(u16 x){ unsigned int u = ((unsigned int)x) << 16; float f; __builtin_memcpy(&f, &u, 4); return f; }
DEV u16 f2bf(float f){ unsigned int u; __builtin_memcpy(&u, &f, 4); unsigned int r = (u + 0x7FFFu + ((u >> 16) & 1u)) >> 16; return (u16)r; }
DEV float sigm(float x){ return 1.f / (1.f + __expf(-x)); }
DEV float tanh_f(float x){ x = fminf(fmaxf(x, -15.f), 15.f); float e = __expf(2.f*x); return (e - 1.f) / (e + 1.f); }

// L3-coherent (agent-scope, relaxed) accessors for cross-XCD mutable state.
DEV void  ast(float* p, float v){ __hip_atomic_store(p, v, __ATOMIC_RELAXED, __HIP_MEMORY_SCOPE_AGENT); }
DEV float ald(const float* p){ return __hip_atomic_load(p, __ATOMIC_RELAXED, __HIP_MEMORY_SCOPE_AGENT); }
DEV void  astu(unsigned int* p, unsigned int v){ __hip_atomic_store(p, v, __ATOMIC_RELAXED, __HIP_MEMORY_SCOPE_AGENT); }
DEV unsigned int aldu(const unsigned int* p){ return __hip_atomic_load(p, __ATOMIC_RELAXED, __HIP_MEMORY_SCOPE_AGENT); }

// ---------------- workspace layout (bytes) ----------------
// G2 layout: [b][g(16)][t(90)][l(240)][128 jj] u16 — block (b,g) slice at step t is one
// contiguous 61,440B run.
static const size_t G_OFF     = 0;            // 353,894,400 B
static const size_t CAMCL_OFF = 0;            // conv temporaries alias over G
static const size_t A1_OFF    = 88473600;
static const size_t A2_OFF    = 154828800;
static const size_t A3_OFF    = 182476800;
static const size_t A4_OFF    = 190771200;
static const size_t A5_OFF    = 201830400;
static const size_t W1B_OFF   = 212889600;
static const size_t W2B_OFF   = 212903936;
static const size_t W3B_OFF   = 212968448;
static const size_t W4B_OFF   = 213075968;
static const size_t W5B_OFF   = 213137408;
static const size_t FEATS_OFF = 353894400;    // fp32 [360][240][64]; dead during scan
static const size_t SC_ALPHA  = 353894400;    // fp32 [4][240] (4KB slot)
static const size_t SC_HX     = 353898496;    // fp32 [2][4][512] = 16KB (parity double-buffer)
static const size_t SC_FLG    = 353914880;    // u32 [4][32]: flags[b*32+g], one 128B line/batch
static const size_t SC_RDY    = 353915392;    // u32 [4] in one 128B line
static const size_t PROJ_OFF  = 376012800;    // fp32 [360][240][64]
static const size_t WWT_OFF   = 398131200;    // fp32 [512][64]   w_w^T
static const size_t WHHP_OFF  = 398262272;    // bf16 [512][2048] whh^T, j-permuted
static const size_t BSUM_OFF  = 400359424;    // fp32 [2048] bih+bhh, j-permuted
static const size_t SW1T_OFF  = 400367616;    // fp32 [512][100]
static const size_t VW1T_OFF  = 400572416;    // fp32 [512][100]
static const size_t HSEQ_OFF  = 400809984;    // fp32 [90][4][512]
static const size_t WS_NEEDED = 401547264;

// ---------------- camera NCHW fp32 -> channels-last bf16 [n][h][w][8] ----------------
__global__ __launch_bounds__(256) void cam_to_cl(const float* __restrict__ cam, u16* __restrict__ out)
{
    int i = blockIdx.x * 256 + threadIdx.x;
    if (i >= NIMG * 96 * 160) return;
    int hw = i % (96 * 160);
    int n  = i / (96 * 160);
    const float* p = cam + (size_t)n * 3 * 96 * 160 + hw;
    bf16x8 v;
    v[0] = (short)f2bf(p[0]);
    v[1] = (short)f2bf(p[15360]);
    v[2] = (short)f2bf(p[30720]);
    v[3] = 0; v[4] = 0; v[5] = 0; v[6] = 0; v[7] = 0;
    *(bf16x8*)&out[(size_t)i * 8] = v;
}

// ---------------- weight prep for convs ----------------
__global__ __launch_bounds__(256) void prep_wbf(
    const float* __restrict__ w, u16* __restrict__ wbf,
    int COUT, int CIN, int CI_PAD, int KHW, int CELLS_PAD, int M_PAD)
{
    int K_PAD = CELLS_PAD * CI_PAD;
    int total = M_PAD * K_PAD;
    for (int i = blockIdx.x * 256 + threadIdx.x; i < total; i += gridDim.x * 256){
        int co = i / K_PAD, kk = i % K_PAD;
        int cell = kk / CI_PAD, ci = kk % CI_PAD;
        float v = 0.f;
        if (co < COUT && cell < KHW * KHW && ci < CIN){
            int kh = cell / KHW, kw = cell % KHW;
            v = w[((size_t)(co * CIN + ci) * KHW + kh) * KHW + kw];
        }
        wbf[i] = f2bf(v);
    }
}

// ---------------- implicit-GEMM MFMA conv (channels-last bf16 in/out) ----------------
template<int CI_PAD, int M_PAD, int COUT, int CO_STORE, int KHW, int CELLS_PAD,
         int S, int P, int HIN, int WIN, int HOUT, int WOUT, int TOH, int TOW>
__global__ __launch_bounds__(256) void conv_mfma(
    const u16* __restrict__ in, const u16* __restrict__ wbf,
    const float* __restrict__ bias, u16* __restrict__ out)
{
    constexpr int K_PAD = CELLS_PAD * CI_PAD;
    constexpr int CP8   = CI_PAD / 8;
    constexpr int TIH   = (TOH - 1) * S + KHW;
    constexpr int TIW   = (TOW - 1) * S + KHW;
    constexpr int TIW_H = (TIW + 1) / 2;
    constexpr int NF    = TOH * TOW / 16;
    constexpr int NK0   = K_PAD / 32;
    constexpr int MF    = M_PAD / 16;
    constexpr int NPW   = (NF + 3) / 4;
    constexpr int LDSE  = (S == 2) ? TIH * CP8 * 2 * TIW_H * 8 : TIH * CP8 * TIW * 8;
    static_assert((TOH * TOW) % 16 == 0, "N tile");
    static_assert(K_PAD % 32 == 0, "K pad");

    __shared__ u16 lds[LDSE];

    int tile = blockIdx.x, n = blockIdx.y;
    constexpr int TW_T = WOUT / TOW;
    int th = tile / TW_T, tw = tile % TW_T;
    int oh0 = th * TOH, ow0 = tw * TOW;
    int ih0 = oh0 * S - P, iw0 = ow0 * S - P;
    int tid = threadIdx.x;

    constexpr int CHUNKS = TIH * TIW * CP8;
    for (int i = tid; i < CHUNKS; i += 256){
        int c8 = i % CP8; int r2 = i / CP8;
        int iw = r2 % TIW, ih = r2 / TIW;
        int ihg = ih0 + ih, iwg = iw0 + iw;
        bf16x8 v = {0,0,0,0,0,0,0,0};
        if (ihg >= 0 && ihg < HIN && iwg >= 0 && iwg < WIN)
            v = *(const bf16x8*)&in[(((size_t)n * HIN + ihg) * WIN + iwg) * CI_PAD + c8 * 8];
        int off;
        if (S == 2) off = (((ih * CP8 + c8) * 2 + (iw & 1)) * TIW_H + (iw >> 1)) * 8;
        else        off = ((ih * CP8 + c8) * TIW + iw) * 8;
        *(bf16x8*)&lds[off] = v;
    }
    __syncthreads();

    int lane = tid & 63, wv = tid >> 6;
    int col = lane & 15, grp = lane >> 4;

    int ihb[NPW], iwb[NPW];
    bool act[NPW];
#pragma unroll
    for (int i2 = 0; i2 < NPW; i2++){
        int nf = wv + i2 * 4;
        act[i2] = (nf < NF);
        int nfc = act[i2] ? nf : 0;
        int nsp = nfc * 16 + col;
        ihb[i2] = (nsp / TOW) * S;
        iwb[i2] = (nsp % TOW) * S;
    }

    f32x4 acc[MF][NPW];
#pragma unroll
    for (int mf = 0; mf < MF; mf++)
#pragma unroll
        for (int i2 = 0; i2 < NPW; i2++)
            acc[mf][i2] = (f32x4){0.f, 0.f, 0.f, 0.f};

    for (int k0 = 0; k0 < NK0; k0++){
        bf16x8 a[MF];
#pragma unroll
        for (int mf = 0; mf < MF; mf++)
            a[mf] = *(const bf16x8*)&wbf[(size_t)(mf * 16 + col) * K_PAD + k0 * 32 + grp * 8];
        int k8 = k0 * 32 + grp * 8;
        int cell = k8 / CI_PAD;
        int ci0  = k8 - cell * CI_PAD;
        if (cell >= KHW * KHW) cell = 0;
        int kh = cell / KHW, kw = cell - (cell / KHW) * KHW;
        int cb = ci0 >> 3;
#pragma unroll
        for (int i2 = 0; i2 < NPW; i2++){
            if (!act[i2]) continue;
            int ih = ihb[i2] + kh;
            int off;
            if (S == 2) off = (((ih * CP8 + cb) * 2 + (kw & 1)) * TIW_H + (iwb[i2] >> 1) + (kw >> 1)) * 8;
            else        off = ((ih * CP8 + cb) * TIW + iwb[i2] + kw) * 8;
            bf16x8 b = *(const bf16x8*)&lds[off];
#pragma unroll
            for (int mf = 0; mf < MF; mf++)
                acc[mf][i2] = __builtin_amdgcn_mfma_f32_16x16x32_bf16(a[mf], b, acc[mf][i2], 0, 0, 0);
        }
    }

#pragma unroll
    for (int i2 = 0; i2 < NPW; i2++){
        if (!act[i2]) continue;
        int nf = wv + i2 * 4;
        int nsp = nf * 16 + col;
        int oh = oh0 + nsp / TOW, ow = ow0 + nsp % TOW;
        size_t obase = (((size_t)n * HOUT + oh) * WOUT + ow) * CO_STORE;
#pragma unroll
        for (int mf = 0; mf < MF; mf++){
            int cobase = mf * 16 + grp * 4;
#pragma unroll
            for (int r = 0; r < 4; r++){
                int co = cobase + r;
                if (co < CO_STORE){
                    float x = (co < COUT) ? fmaxf(acc[mf][i2][r] + bias[co], 0.f) : 0.f;
                    out[obase + co] = f2bf(x);
                }
            }
        }
    }
}

// ---------------- feats rearrange ----------------
__global__ __launch_bounds__(256) void extract_feats(const u16* __restrict__ a5, float* __restrict__ feats)
{
    int idx = blockIdx.x * 256 + threadIdx.x;
    if (idx >= NIMG * 12 * 20 * 64) return;
    int c = idx & 63; int t1 = idx >> 6;
    int w = t1 % 20; t1 /= 20;
    int h = t1 % 12; int n = t1 / 12;
    float v = bf2f(a5[idx]);
    int flat = w * 768 + c * 12 + h;
    int d = flat / 240, l = flat % 240;
    feats[((size_t)n * LL + l) * DD + d] = v;
}

// ---------------- proj = feats @ proj_w.T + proj_b  (64 rows per block) ----------------
__global__ __launch_bounds__(256) void proj_kernel2(
    const float* __restrict__ feats, const float* __restrict__ pw,
    const float* __restrict__ pb, float* __restrict__ proj)
{
    __shared__ float pws[64][65];   // [d][dd]
    __shared__ float fs[64][64];    // [r][d]
    int tid = threadIdx.x;
    size_t R0 = (size_t)blockIdx.x * 64;
    for (int i = tid; i < 4096; i += 256){
        int dd = i >> 6, d = i & 63;
        pws[d][dd] = pw[dd * 64 + d];
    }
    for (int i = tid; i < 4096; i += 256){
        int r = i >> 6, d = i & 63;
        fs[r][d] = feats[(R0 + r) * 64 + d];
    }
    __syncthreads();
    for (int i = tid; i < 4096; i += 256){
        int r = i >> 6, dd = i & 63;
        float a = pb[dd];
#pragma unroll
        for (int d = 0; d < 64; d++) a = fmaf(fs[r][d], pws[d][dd], a);
        proj[(R0 + r) * 64 + dd] = a;
    }
}

// ---------------- prep: whh permute, bias combine, w_w transpose ----------------
__global__ __launch_bounds__(256) void prep(
    const float* __restrict__ w_w, const float* __restrict__ whh,
    const float* __restrict__ bih, const float* __restrict__ bhh,
    float* __restrict__ w_wT, u16* __restrict__ whh_p, float* __restrict__ bsum)
{
    int idx = blockIdx.x * 256 + threadIdx.x;
    int stride = gridDim.x * 256;
    for (int i = idx; i < 512*64; i += stride){
        int k = i / 64, dd = i % 64;
        w_wT[i] = w_w[dd*512 + k];
    }
    for (int i = idx; i < 512*2048; i += stride){
        int k = i / 2048, jj = i % 2048;
        int u = jj >> 2, g = jj & 3, j = g*512 + u;
        whh_p[i] = f2bf(whh[(size_t)j*512 + k]);
    }
    for (int i = idx; i < 2048; i += stride){
        int u = i >> 2, g = i & 3, j = g*512 + u;
        bsum[i] = bih[j] + bhh[j];
    }
}

// ---------------- prep2: MLP first-layer transposes ----------------
__global__ __launch_bounds__(256) void prep2(
    const float* __restrict__ sw1, const float* __restrict__ vw1,
    float* __restrict__ sw1T, float* __restrict__ vw1T)
{
    int idx = blockIdx.x * 256 + threadIdx.x;
    int stride = gridDim.x * 256;
    for (int i = idx; i < 512*100; i += stride){
        int k = i / 100, u = i % 100;
        sw1T[i] = sw1[u*512 + k];
        vw1T[i] = vw1[u*512 + k];
    }
}

// ---------------- gcompute via MFMA; G2 slice-contiguous layout ----------------
__global__ __launch_bounds__(256, 2) void gcompute_mfma2(
    const float* __restrict__ feats, const float* __restrict__ wih, u16* __restrict__ G)
{
    __shared__ u16 Bsw[256 * 64];
    __shared__ u16 Asw[128 * 64];
    float (*obuf)[1024] = (float(*)[1024])Asw;

    int jt = blockIdx.x, l = blockIdx.y;
    int j0 = jt * 256;
    int tid = threadIdx.x;
    int g8 = tid & 7;

    for (int p = 0; p < 8; p++){
        int row = p * 32 + (tid >> 3);
        int jj = j0 + row;
        int j = (jj & 3) * 512 + (jj >> 2);
        const float* src = wih + (size_t)j * 15360 + l * 64 + g8 * 8;
        float4 v0 = *(const float4*)src;
        float4 v1 = *(const float4*)(src + 4);
        bf16x8 pk;
        pk[0]=(short)f2bf(v0.x); pk[1]=(short)f2bf(v0.y); pk[2]=(short)f2bf(v0.z); pk[3]=(short)f2bf(v0.w);
        pk[4]=(short)f2bf(v1.x); pk[5]=(short)f2bf(v1.y); pk[6]=(short)f2bf(v1.z); pk[7]=(short)f2bf(v1.w);
        *(bf16x8*)&Bsw[(row * 8 + (g8 ^ (row & 7))) * 8] = pk;
    }
    __syncthreads();

    int lane = tid & 63, w = tid >> 6;
    int col = lane & 15, grp = lane >> 4;

    bf16x8 bfr[2][4];
#pragma unroll
    for (int k0 = 0; k0 < 2; k0++)
#pragma unroll
        for (int nf = 0; nf < 4; nf++){
            int row = w * 64 + nf * 16 + col;
            bfr[k0][nf] = *(const bf16x8*)&Bsw[(row * 8 + ((k0 * 4 + grp) ^ (row & 7))) * 8];
        }

    for (int mt = 0; mt < 3; mt++){
        int m0 = mt * 128;
        __syncthreads();
        for (int p = 0; p < 4; p++){
            int row = p * 32 + (tid >> 3);
            const float* src = feats + ((size_t)(m0 + row) * LL + l) * DD + g8 * 8;
            float4 v0 = *(const float4*)src;
            float4 v1 = *(const float4*)(src + 4);
            bf16x8 pk;
            pk[0]=(short)f2bf(v0.x); pk[1]=(short)f2bf(v0.y); pk[2]=(short)f2bf(v0.z); pk[3]=(short)f2bf(v0.w);
            pk[4]=(short)f2bf(v1.x); pk[5]=(short)f2bf(v1.y); pk[6]=(short)f2bf(v1.z); pk[7]=(short)f2bf(v1.w);
            *(bf16x8*)&Asw[(row * 8 + (g8 ^ (row & 7))) * 8] = pk;
        }
        __syncthreads();

        f32x4 acc[8][4];
#pragma unroll
        for (int mf = 0; mf < 8; mf++)
#pragma unroll
            for (int nf = 0; nf < 4; nf++) acc[mf][nf] = (f32x4){0.f,0.f,0.f,0.f};

#pragma unroll
        for (int k0 = 0; k0 < 2; k0++){
#pragma unroll
            for (int mf = 0; mf < 8; mf++){
                int row = mf * 16 + col;
                bf16x8 a = *(const bf16x8*)&Asw[(row * 8 + ((k0 * 4 + grp) ^ (row & 7))) * 8];
#pragma unroll
                for (int nf = 0; nf < 4; nf++)
                    acc[mf][nf] = __builtin_amdgcn_mfma_f32_16x16x32_bf16(a, bfr[k0][nf], acc[mf][nf], 0, 0, 0);
            }
        }
        __syncthreads();

#pragma unroll
        for (int mf = 0; mf < 8; mf++){
#pragma unroll
            for (int nf = 0; nf < 4; nf++)
#pragma unroll
                for (int r = 0; r < 4; r++)
                    obuf[w][(grp * 4 + r) * 64 + nf * 16 + col] = acc[mf][nf][r];
#pragma unroll
            for (int p = 0; p < 2; p++){
                int rloc = p * 8 + (lane >> 3);
                int c0 = (lane & 7) * 8;
                float4 r0 = *(const float4*)&obuf[w][rloc * 64 + c0];
                float4 r1 = *(const float4*)&obuf[w][rloc * 64 + c0 + 4];
                int m = m0 + mf * 16 + rloc;
                if (m < NIMG){
                    int b = m / NT, tt = m % NT;
                    int jj8 = j0 + w * 64 + c0;
                    int gg2 = jj8 >> 7, jjl = jj8 & 127;
                    bf16x8 pk;
                    pk[0]=(short)f2bf(r0.x); pk[1]=(short)f2bf(r0.y); pk[2]=(short)f2bf(r0.z); pk[3]=(short)f2bf(r0.w);
                    pk[4]=(short)f2bf(r1.x); pk[5]=(short)f2bf(r1.y); pk[6]=(short)f2bf(r1.z); pk[7]=(short)f2bf(r1.w);
                    *(bf16x8*)&G[(((size_t)(b * GPB + gg2) * NT + tt) * LL + l) * 128 + jjl] = pk;
                }
            }
        }
    }
}

// ---------------- persistent batch-partitioned scan (4 x [1 attn + 16 gates]) ----------------
// Critical-path trimmed: gates blocks stage h(t-1) on the flag line (available before alpha)
// and compute the whh term WHILE the attn block computes alpha(t); after rdy only the
// 30-l G-sum remains. Gates arrivals are parallel flag stores (no RMW chain).
__global__ __launch_bounds__(256) void scan_pc(
    const u16* __restrict__ G, const u16* __restrict__ whh_p,
    const float* __restrict__ bsum, const float* __restrict__ proj,
    const float* __restrict__ w_wT, const float* __restrict__ w_b,
    const float* __restrict__ waw, const float* __restrict__ wab,
    float* __restrict__ alpha_g, float* __restrict__ hx_g,
    unsigned int* __restrict__ flg, unsigned int* __restrict__ rdy,
    float* __restrict__ hseq)
{
    int tid = threadIdx.x, blk = blockIdx.x;

    if (blk < NB){
        // ================= ATTN BLOCK (batch b) =================
        __shared__ float projT[DD * 241];  // 61.7KB transposed proj: [d][l]
        __shared__ float hloc[HID];        // 2KB
        __shared__ float apjs[DD];         // 256B
        __shared__ float scr[256];         // 1KB (gemv partials / es values)
        int b = blk;
        float wb0 = wab[0];

        // init: stage proj(0) transposed, alpha(0) with hx=0, rdy=1
        {
            const float* src = proj + ((size_t)(b * NT + 0)) * LL * DD;
            for (int it = 0; it < 15; it++){
                int i4 = it * 256 + tid;
                int l = i4 >> 4, d0 = (i4 & 15) * 4;
                float4 v = *(const float4*)&src[l * 64 + d0];
                projT[(d0 + 0) * 241 + l] = v.x;
                projT[(d0 + 1) * 241 + l] = v.y;
                projT[(d0 + 2) * 241 + l] = v.z;
                projT[(d0 + 3) * 241 + l] = v.w;
            }
        }
        if (tid < DD) apjs[tid] = w_b[tid];
        __syncthreads();
        if (tid < LL){
            float e = 0.f;
#pragma unroll
            for (int d = 0; d < DD; d++)
                e = fmaf(tanh_f(projT[d * 241 + tid] + apjs[d]), waw[d], e);
            scr[tid] = e + wb0;
        }
        __syncthreads();
        if (tid < 64){
            float m = -1e30f;
            for (int l = tid; l < LL; l += 64) m = fmaxf(m, scr[l]);
#pragma unroll
            for (int off = 32; off; off >>= 1) m = fmaxf(m, __shfl_xor(m, off));
            float ex[4]; int c = 0; float ssum = 0.f;
            for (int l = tid; l < LL; l += 64){ float e2 = __expf(scr[l] - m); ex[c++] = e2; ssum += e2; }
#pragma unroll
            for (int off = 32; off; off >>= 1) ssum += __shfl_xor(ssum, off);
            float inv = 1.f / ssum; c = 0;
            for (int l = tid; l < LL; l += 64) ast(&alpha_g[b * LL + l], ex[c++] * inv);
        }
        __syncthreads();
        if (tid == 0) astu(&rdy[b], 1u);

        for (int t = 0; t < NT - 1; t++){
            // waves 1-3 stage proj(t+1) transposed; wave 0 polls the 16 flags concurrently
            if (tid >= 64){
                int idx = tid - 64;
                const float* src = proj + ((size_t)(b * NT + t + 1)) * LL * DD;
#pragma unroll
                for (int it = 0; it < 20; it++){
                    int i4 = it * 192 + idx;
                    int l = i4 >> 4, d0 = (i4 & 15) * 4;
                    float4 v = *(const float4*)&src[l * 64 + d0];
                    projT[(d0 + 0) * 241 + l] = v.x;
                    projT[(d0 + 1) * 241 + l] = v.y;
                    projT[(d0 + 2) * 241 + l] = v.z;
                    projT[(d0 + 3) * 241 + l] = v.w;
                }
            } else if (tid < GPB){
                int g = 0;
                while (aldu(&flg[b * 32 + tid]) < (unsigned int)(t + 1)){
                    if (++g > (1 << 24)) break;
                    __builtin_amdgcn_s_sleep(1);
                }
            }
            __syncthreads();

            // stage h(t) from parity buffer
            {
                const float* hsrc = hx_g + (size_t)((t + 1) & 1) * (NB * HID) + b * HID;
                hloc[tid] = ald(&hsrc[tid]);
                hloc[tid + 256] = ald(&hsrc[tid + 256]);
            }
            __syncthreads();

            // apj gemv (4-way k split)
            {
                int dd = tid & 63, dq = tid >> 6;
                float p = 0.f;
                for (int ki = 0; ki < 128; ki++){
                    int k = dq * 128 + ki;
                    p = fmaf(hloc[k], w_wT[k * 64 + dd], p);
                }
                scr[dq * 64 + dd] = p;
            }
            __syncthreads();
            if (tid < 64) apjs[tid] = w_b[tid] + scr[tid] + scr[64 + tid] + scr[128 + tid] + scr[192 + tid];
            __syncthreads();
            // es (conflict-free projT reads) + softmax
            float ev = 0.f;
            if (tid < LL){
#pragma unroll
                for (int d = 0; d < DD; d++)
                    ev = fmaf(tanh_f(projT[d * 241 + tid] + apjs[d]), waw[d], ev);
                ev += wb0;
            }
            __syncthreads();
            if (tid < LL) scr[tid] = ev;
            __syncthreads();
            if (tid < 64){
                float m = -1e30f;
                for (int l = tid; l < LL; l += 64) m = fmaxf(m, scr[l]);
#pragma unroll
                for (int off = 32; off; off >>= 1) m = fmaxf(m, __shfl_xor(m, off));
                float ex[4]; int c = 0; float ssum = 0.f;
                for (int l = tid; l < LL; l += 64){ float e2 = __expf(scr[l] - m); ex[c++] = e2; ssum += e2; }
#pragma unroll
                for (int off = 32; off; off >>= 1) ssum += __shfl_xor(ssum, off);
                float inv = 1.f / ssum; c = 0;
                for (int l = tid; l < LL; l += 64) ast(&alpha_g[b * LL + l], ex[c++] * inv);
            }
            __syncthreads();
            if (tid == 0) astu(&rdy[b], (unsigned int)(t + 2));
        }
    } else {
        // ================= GATES BLOCK (batch b, group g) =================
        __shared__ float als[LL];        // 960B
        __shared__ float hxs[HID];       // 2KB
        __shared__ float red[8][128];    // 4KB
        __shared__ float gat[128];       // 512B
        __shared__ float cxl[32];        // 128B
        int idx = blk - NB;
        int b = idx & 3, g = idx >> 2;
        int jq = tid & 31, lg = tid >> 5;       // 32 jj-quads x 8 l/k-groups
        const size_t SLICE = (size_t)LL * 128;
        const u16* gbase0 = G + ((size_t)(b * GPB + g) * NT) * SLICE;

        if (tid < 32) cxl[tid] = 0.f;

        float sink = 0.f;
        // initial prefetch G(0) on waves 1-3 (consumed at first loop top)
        if (tid >= 64){
            int pidx = tid - 64;
            const float4* pp = (const float4*)(gbase0);
            float s2 = 0.f;
#pragma unroll
            for (int i = 0; i < 20; i++){ float4 v = pp[i * 192 + pidx]; s2 += v.x + v.w; }
            sink = s2;
        }

        for (int t = 0; t < NT; t++){
            // ---- early: h(t-1) (flag line precedes alpha availability) ----
            if (t == 0){
                hxs[tid] = 0.f; hxs[tid + 256] = 0.f;
                __syncthreads();
            } else {
                if (tid < GPB){
                    int gu = 0;
                    while (aldu(&flg[b * 32 + tid]) < (unsigned int)t){
                        if (++gu > (1 << 24)) break;
                        __builtin_amdgcn_s_sleep(1);
                    }
                }
                __syncthreads();
                const float* hsrc = hx_g + (size_t)(t & 1) * (NB * HID) + b * HID;
                hxs[tid] = ald(&hsrc[tid]);
                hxs[tid + 256] = ald(&hsrc[tid + 256]);
                __syncthreads();
            }
            asm volatile("" :: "v"(sink));   // consume previous G prefetch (already complete)

            // ---- whh term NOW (overlaps attn's alpha computation) ----
            float ac0 = 0.f, ac1 = 0.f, ac2 = 0.f, ac3 = 0.f;
            {
                const u16* wp = whh_p + (size_t)(lg * 64) * NJ + g * 128 + jq * 4;
#pragma unroll 8
                for (int ki = 0; ki < 64; ki++){
                    short4 wv = *(const short4*)(wp + (size_t)ki * NJ);
                    float h = hxs[lg * 64 + ki];
                    ac0 = fmaf(h, bf2f((u16)wv.x), ac0);
                    ac1 = fmaf(h, bf2f((u16)wv.y), ac1);
                    ac2 = fmaf(h, bf2f((u16)wv.z), ac2);
                    ac3 = fmaf(h, bf2f((u16)wv.w), ac3);
                }
            }

            // ---- wait alpha(t), stage it ----
            if (tid == 0){
                int gu = 0;
                while (aldu(&rdy[b]) < (unsigned int)(t + 1)){
                    if (++gu > (1 << 24)) break;
                    __builtin_amdgcn_s_sleep(1);
                }
            }
            __syncthreads();
            if (tid < LL) als[tid] = ald(&alpha_g[b * LL + tid]);
            __syncthreads();

            // ---- G-sum (30 l, L2-hot contiguous) ----
            {
                const u16* gp = gbase0 + (size_t)t * SLICE + (size_t)(lg * 30) * 128 + jq * 4;
#pragma unroll 6
                for (int i = 0; i < 30; i++){
                    short4 gv = *(const short4*)(gp + i * 128);
                    float al = als[lg * 30 + i];
                    ac0 = fmaf(al, bf2f((u16)gv.x), ac0);
                    ac1 = fmaf(al, bf2f((u16)gv.y), ac1);
                    ac2 = fmaf(al, bf2f((u16)gv.z), ac2);
                    ac3 = fmaf(al, bf2f((u16)gv.w), ac3);
                }
            }
            red[lg][jq * 4 + 0] = ac0;
            red[lg][jq * 4 + 1] = ac1;
            red[lg][jq * 4 + 2] = ac2;
            red[lg][jq * 4 + 3] = ac3;
            __syncthreads();
            if (tid < 128){
                float v = 0.f;
#pragma unroll
                for (int q = 0; q < 8; q++) v += red[q][tid];
                gat[tid] = v;
            }
            __syncthreads();

            // local pointwise cell for units [g*32, g*32+32)
            if (tid < 32){
                int jjb = g * 128 + tid * 4;
                float4 bs = *(const float4*)&bsum[jjb];
                float gi = gat[tid*4 + 0] + bs.x;
                float gf = gat[tid*4 + 1] + bs.y;
                float gg = gat[tid*4 + 2] + bs.z;
                float go = gat[tid*4 + 3] + bs.w;
                float c = sigm(gf) * cxl[tid] + sigm(gi) * tanhf(gg);
                cxl[tid] = c;
                float h = sigm(go) * tanhf(c);
                int u = g * 32 + tid;
                ast(&hx_g[(size_t)((t + 1) & 1) * (NB * HID) + b * HID + u], h);
                hseq[((size_t)t * NB + b) * HID + u] = h;
            }
            __syncthreads();          // drains h stores (vmcnt 0 before barrier)
            if (tid == 0) astu(&flg[b * 32 + g], (unsigned int)(t + 1));

            // prefetch G(t+1) on waves 1-3 ONLY; no immediate consume
            if (t < NT - 1 && tid >= 64){
                int pidx = tid - 64;
                const float4* pp = (const float4*)(gbase0 + (size_t)(t + 1) * SLICE);
                float s2 = 0.f;
#pragma unroll
                for (int i = 0; i < 20; i++){ float4 v = pp[i * 192 + pidx]; s2 += v.x + v.w; }
                sink = s2;
            }
        }
    }
}

// ---------------- MLP heads ----------------
__global__ __launch_bounds__(256) void mlp_kernel(
    const float* __restrict__ hseq,
    const float* __restrict__ sw1T, const float* __restrict__ sb1,
    const float* __restrict__ sw2,  const float* __restrict__ sb2,
    const float* __restrict__ sw3,  const float* __restrict__ sb3,
    const float* __restrict__ sw4,  const float* __restrict__ sb4,
    const float* __restrict__ vw1T, const float* __restrict__ vb1,
    const float* __restrict__ vw2,  const float* __restrict__ vb2,
    const float* __restrict__ vw3,  const float* __restrict__ vb3,
    const float* __restrict__ vw4,  const float* __restrict__ vb4,
    float* __restrict__ out)
{
    __shared__ float h0[HID];
    __shared__ float h1[2][100];
    __shared__ float h2[2][52];
    __shared__ float h3[2][12];
    int tb = blockIdx.x;
    int tid = threadIdx.x;
    for (int i = tid; i < HID; i += 256) h0[i] = hseq[(size_t)tb * HID + i];
    __syncthreads();
    if (tid < 100){
        float a = sb1[tid];
        for (int k = 0; k < HID; k++) a = fmaf(h0[k], sw1T[k*100 + tid], a);
        h1[0][tid] = fmaxf(a, 0.f);
    } else if (tid >= 128 && tid < 228){
        int u = tid - 128;
        float a = vb1[u];
        for (int k = 0; k < HID; k++) a = fmaf(h0[k], vw1T[k*100 + u], a);
        h1[1][u] = fmaxf(a, 0.f);
    }
    __syncthreads();
    if (tid < 50){
        float a = sb2[tid];
        for (int k = 0; k < 100; k++) a = fmaf(h1[0][k], sw2[tid*100 + k], a);
        h2[0][tid] = fmaxf(a, 0.f);
    } else if (tid >= 128 && tid < 178){
        int u = tid - 128;
        float a = vb2[u];
        for (int k = 0; k < 100; k++) a = fmaf(h1[1][k], vw2[u*100 + k], a);
        h2[1][u] = fmaxf(a, 0.f);
    }
    __syncthreads();
    if (tid < 10){
        float a = sb3[tid];
        for (int k = 0; k < 50; k++) a = fmaf(h2[0][k], sw3[tid*50 + k], a);
        h3[0][tid] = fmaxf(a, 0.f);
    } else if (tid >= 128 && tid < 138){
        int u = tid - 128;
        float a = vb3[u];
        for (int k = 0; k < 50; k++) a = fmaf(h2[1][k], vw3[u*50 + k], a);
        h3[1][u] = fmaxf(a, 0.f);
    }
    __syncthreads();
    if (tid == 0){
        float a = sb4[0];
        for (int k = 0; k < 10; k++) a = fmaf(h3[0][k], sw4[k], a);
        out[tb] = a;
    } else if (tid == 128){
        float a = vb4[0];
        for (int k = 0; k < 10; k++) a = fmaf(h3[1][k], vw4[k], a);
        out[360 + tb] = a;
    }
}

extern "C" void kernel_launch(void* const* d_in, const int* in_sizes, int n_in,
                              void* d_out, int out_size, void* d_ws, size_t ws_size,
                              hipStream_t stream)
{
    (void)in_sizes; (void)n_in; (void)out_size;
    if (ws_size < WS_NEEDED) return;

    const float* cam   = (const float*)d_in[0];
    const float* cw1   = (const float*)d_in[1];  const float* cb1 = (const float*)d_in[2];
    const float* cw2   = (const float*)d_in[3];  const float* cb2 = (const float*)d_in[4];
    const float* cw3   = (const float*)d_in[5];  const float* cb3 = (const float*)d_in[6];
    const float* cw4   = (const float*)d_in[7];  const float* cb4 = (const float*)d_in[8];
    const float* cw5   = (const float*)d_in[9];  const float* cb5 = (const float*)d_in[10];
    const float* pw    = (const float*)d_in[11]; const float* pb  = (const float*)d_in[12];
    const float* w_w   = (const float*)d_in[13]; const float* w_b = (const float*)d_in[14];
    const float* waw   = (const float*)d_in[15]; const float* wab = (const float*)d_in[16];
    const float* wih   = (const float*)d_in[17]; const float* whh = (const float*)d_in[18];
    const float* bih   = (const float*)d_in[19]; const float* bhh = (const float*)d_in[20];
    const float* sw1   = (const float*)d_in[21]; const float* sb1 = (const float*)d_in[22];
    const float* sw2   = (const float*)d_in[23]; const float* sb2 = (const float*)d_in[24];
    const float* sw3   = (const float*)d_in[25]; const float* sb3 = (const float*)d_in[26];
    const float* sw4   = (const float*)d_in[27]; const float* sb4 = (const float*)d_in[28];
    const float* vw1   = (const float*)d_in[29]; const float* vb1 = (const float*)d_in[30];
    const float* vw2   = (const float*)d_in[31]; const float* vb2 = (const float*)d_in[32];
    const float* vw3   = (const float*)d_in[33]; const float* vb3 = (const float*)d_in[34];
    const float* vw4   = (const float*)d_in[35]; const float* vb4 = (const float*)d_in[36];

    char* ws = (char*)d_ws;
    u16*   camcl = (u16*)(ws + CAMCL_OFF);
    u16*   a1    = (u16*)(ws + A1_OFF);
    u16*   a2    = (u16*)(ws + A2_OFF);
    u16*   a3    = (u16*)(ws + A3_OFF);
    u16*   a4    = (u16*)(ws + A4_OFF);
    u16*   a5    = (u16*)(ws + A5_OFF);
    u16*   w1b   = (u16*)(ws + W1B_OFF);
    u16*   w2b   = (u16*)(ws + W2B_OFF);
    u16*   w3b   = (u16*)(ws + W3B_OFF);
    u16*   w4b   = (u16*)(ws + W4B_OFF);
    u16*   w5b   = (u16*)(ws + W5B_OFF);
    float* feats = (float*)(ws + FEATS_OFF);
    float* proj  = (float*)(ws + PROJ_OFF);
    float* w_wT  = (float*)(ws + WWT_OFF);
    u16*   whh_p = (u16*)  (ws + WHHP_OFF);
    float* bsum  = (float*)(ws + BSUM_OFF);
    float* sw1T  = (float*)(ws + SW1T_OFF);
    float* vw1T  = (float*)(ws + VW1T_OFF);
    float* alpha = (float*)(ws + SC_ALPHA);
    float* hx_g  = (float*)(ws + SC_HX);
    unsigned int* flg = (unsigned int*)(ws + SC_FLG);
    unsigned int* rdy = (unsigned int*)(ws + SC_RDY);
    float* hseq  = (float*)(ws + HSEQ_OFF);
    u16*   G     = (u16*)  (ws + G_OFF);

    cam_to_cl<<<(NIMG*96*160 + 255)/256, 256, 0, stream>>>(cam, camcl);
    prep_wbf<<<64, 256, 0, stream>>>(cw1, w1b, 24,  3,  8, 5, 28, 32);
    prep_wbf<<<64, 256, 0, stream>>>(cw2, w2b, 36, 24, 24, 5, 28, 48);
    prep_wbf<<<64, 256, 0, stream>>>(cw3, w3b, 48, 36, 40, 5, 28, 48);
    prep_wbf<<<64, 256, 0, stream>>>(cw4, w4b, 64, 48, 48, 3, 10, 64);
    prep_wbf<<<64, 256, 0, stream>>>(cw5, w5b, 64, 64, 64, 3,  9, 64);

    conv_mfma<   8,    32,   24,  24,   5,  28,   2, 2, 96, 160, 48, 80,  8, 40>
        <<<dim3(12, NIMG), 256, 0, stream>>>(camcl, w1b, cb1, a1);
    conv_mfma<  24,    48,   36,  40,   5,  28,   2, 2, 48,  80, 24, 40,  8, 20>
        <<<dim3(6, NIMG), 256, 0, stream>>>(a1, w2b, cb2, a2);
    conv_mfma<  40,    48,   48,  48,   5,  28,   2, 2, 24,  40, 12, 20, 12, 20>
        <<<dim3(1, NIMG), 256, 0, stream>>>(a2, w3b, cb3, a3);
    conv_mfma<  48,    64,   64,  64,   3,  10,   1, 1, 12,  20, 12, 20, 12, 20>
        <<<dim3(1, NIMG), 256, 0, stream>>>(a3, w4b, cb4, a4);
    conv_mfma<  64,    64,   64,  64,   3,   9,   1, 1, 12,  20, 12, 20, 12, 20>
        <<<dim3(1, NIMG), 256, 0, stream>>>(a4, w5b, cb5, a5);

    extract_feats<<<(NIMG*12*20*64 + 255)/256, 256, 0, stream>>>(a5, feats);
    proj_kernel2<<<NIMG*LL/64, 256, 0, stream>>>(feats, pw, pb, proj);
    prep<<<1024, 256, 0, stream>>>(w_w, whh, bih, bhh, w_wT, whh_p, bsum);
    gcompute_mfma2<<<dim3(8, 240), 256, 0, stream>>>(feats, wih, G);

    // zero scan state: alpha(4KB) + hx parity buffers(16KB) + flags(512B) + rdy(128B)
    hipMemsetAsync(ws + SC_ALPHA, 0, 21120, stream);

    scan_pc<<<TBLK, 256, 0, stream>>>(G, whh_p, bsum, proj, w_wT, w_b, waw, wab,
                                      alpha, hx_g, flg, rdy, hseq);

    prep2<<<256, 256, 0, stream>>>(sw1, vw1, sw1T, vw1T);

    mlp_kernel<<<360, 256, 0, stream>>>(hseq,
        sw1T, sb1, sw2, sb2, sw3, sb3, sw4, sb4,
        vw1T, vb1, vw2, vb2, vw3, vb3, vw4, vb4, (float*)d_out);
}

// Round 15
// 1398.509 us; speedup vs baseline: 1.3668x; 1.0167x over previous
//
#include <hip/hip_runtime.h>
#include <hip/hip_bf16.h>

typedef unsigned short u16;
using bf16x8 = __attribute__((ext_vector_type(8))) short;
using f32x4  = __attribute__((ext_vector_type(4))) float;

#define NB   4
#define NT   90
#define NIMG 360
#define LL   240
#define DD   64
#define HID  512
#define NJ   2048
#define GPB  16          // gates blocks per batch
#define TBLK (NB + NB*GPB) // 4 attn + 64 gates = 68

#define DEV __device__ __forceinline__

DEV float bf2f(u16 x){ unsigned int u = ((unsigned int)x) << 16; float f; __builtin_memcpy(&f, &u, 4); return f; }
DEV u16 f2bf(float f){ unsigned int u; __builtin_memcpy(&u, &f, 4); unsigned int r = (u + 0x7FFFu + ((u >> 16) & 1u)) >> 16; return (u16)r; }
DEV unsigned int f2u(float f){ unsigned int u; __builtin_memcpy(&u, &f, 4); return u; }
DEV float sigm(float x){ return 1.f / (1.f + __expf(-x)); }
DEV float tanh_f(float x){ x = fminf(fmaxf(x, -15.f), 15.f); float e = __expf(2.f*x); return (e - 1.f) / (e + 1.f); }

// L3-coherent (agent-scope, relaxed) accessors for cross-XCD mutable state.
DEV void  ast(float* p, float v){ __hip_atomic_store(p, v, __ATOMIC_RELAXED, __HIP_MEMORY_SCOPE_AGENT); }
DEV float ald(const float* p){ return __hip_atomic_load(p, __ATOMIC_RELAXED, __HIP_MEMORY_SCOPE_AGENT); }
DEV void  astu(unsigned int* p, unsigned int v){ __hip_atomic_store(p, v, __ATOMIC_RELAXED, __HIP_MEMORY_SCOPE_AGENT); }
DEV unsigned int aldu(const unsigned int* p){ return __hip_atomic_load(p, __ATOMIC_RELAXED, __HIP_MEMORY_SCOPE_AGENT); }

// ---------------- workspace layout (bytes) ----------------
// G2 layout: [b][g(16)][t(90)][l(240)][128 jj] u16 — block (b,g) slice at step t is one
// contiguous 61,440B run.
static const size_t G_OFF     = 0;            // 353,894,400 B
static const size_t A1_OFF    = 88473600;     // conv temporaries alias over G
static const size_t A2_OFF    = 154828800;
static const size_t A3_OFF    = 182476800;
static const size_t A4_OFF    = 190771200;
static const size_t A5_OFF    = 201830400;
static const size_t W1B_OFF   = 212889600;
static const size_t W2B_OFF   = 212903936;
static const size_t W3B_OFF   = 212968448;
static const size_t W4B_OFF   = 213075968;
static const size_t W5B_OFF   = 213137408;
static const size_t FEATS_OFF = 353894400;    // fp32 [360][240][64]; dead during scan
static const size_t SC_ALPHA  = 353894400;    // fp32 [4][240] (4KB slot) — sentinel-signed
static const size_t SC_HX     = 353898496;    // fp32 [2][4][512] = 16KB (parity double-buffer)
static const size_t SC_FLG    = 353914880;    // u32 [4][32]: flags[b*32+g], one 128B line/batch
static const size_t PROJ_OFF  = 376012800;    // fp32 [360][240][64]
static const size_t WWT_OFF   = 398131200;    // fp32 [512][64]   w_w^T
static const size_t WHHP_OFF  = 398262272;    // bf16 [512][2048] whh^T, j-permuted
static const size_t BSUM_OFF  = 400359424;    // fp32 [2048] bih+bhh, j-permuted
static const size_t SW1T_OFF  = 400367616;    // fp32 [512][100]
static const size_t VW1T_OFF  = 400572416;    // fp32 [512][100]
static const size_t HSEQ_OFF  = 400809984;    // fp32 [90][4][512]
static const size_t WS_NEEDED = 401547264;

// ---------------- weight prep for convs ----------------
__global__ __launch_bounds__(256) void prep_wbf(
    const float* __restrict__ w, u16* __restrict__ wbf,
    int COUT, int CIN, int CI_PAD, int KHW, int CELLS_PAD, int M_PAD)
{
    int K_PAD = CELLS_PAD * CI_PAD;
    int total = M_PAD * K_PAD;
    for (int i = blockIdx.x * 256 + threadIdx.x; i < total; i += gridDim.x * 256){
        int co = i / K_PAD, kk = i % K_PAD;
        int cell = kk / CI_PAD, ci = kk % CI_PAD;
        float v = 0.f;
        if (co < COUT && cell < KHW * KHW && ci < CIN){
            int kh = cell / KHW, kw = cell % KHW;
            v = w[((size_t)(co * CIN + ci) * KHW + kh) * KHW + kw];
        }
        wbf[i] = f2bf(v);
    }
}

// ---------------- conv1: fused camera fp32 -> LDS bf16 staging + implicit-GEMM MFMA ---------
// CI_PAD=8 (3 real ch), M_PAD=32, COUT=24, KHW=5, CELLS_PAD=28, S=2, P=2,
// HIN=96, WIN=160, HOUT=48, WOUT=80, TOH=8, TOW=40.
__global__ __launch_bounds__(256) void conv1_mfma(
    const float* __restrict__ cam, const u16* __restrict__ wbf,
    const float* __restrict__ bias, u16* __restrict__ out)
{
    constexpr int K_PAD = 224, TIH = 19, TIW = 83, TIW_H = 42;
    constexpr int NK0 = 7, MF = 2, NPW = 5;
    __shared__ u16 lds[TIH * 2 * TIW_H * 8];   // 25.5KB

    int tile = blockIdx.x, n = blockIdx.y;
    int th = tile >> 1, tw = tile & 1;
    int oh0 = th * 8, ow0 = tw * 40;
    int ih0 = oh0 * 2 - 2, iw0 = ow0 * 2 - 2;
    int tid = threadIdx.x;

    const float* cam0 = cam + (size_t)n * 3 * 96 * 160;
    for (int i = tid; i < TIH * TIW; i += 256){
        int iw = i % TIW, ih = i / TIW;
        int ihg = ih0 + ih, iwg = iw0 + iw;
        bf16x8 v = {0,0,0,0,0,0,0,0};
        if (ihg >= 0 && ihg < 96 && iwg >= 0 && iwg < 160){
            int p = ihg * 160 + iwg;
            v[0] = (short)f2bf(cam0[p]);
            v[1] = (short)f2bf(cam0[15360 + p]);
            v[2] = (short)f2bf(cam0[30720 + p]);
        }
        int off = ((ih * 2 + (iw & 1)) * TIW_H + (iw >> 1)) * 8;
        *(bf16x8*)&lds[off] = v;
    }
    __syncthreads();

    int lane = tid & 63, wv = tid >> 6;
    int col = lane & 15, grp = lane >> 4;

    int ihb[NPW], iwb[NPW];
#pragma unroll
    for (int i2 = 0; i2 < NPW; i2++){
        int nsp = (wv + i2 * 4) * 16 + col;
        ihb[i2] = (nsp / 40) * 2;
        iwb[i2] = (nsp % 40) * 2;
    }

    f32x4 acc[MF][NPW];
#pragma unroll
    for (int mf = 0; mf < MF; mf++)
#pragma unroll
        for (int i2 = 0; i2 < NPW; i2++)
            acc[mf][i2] = (f32x4){0.f, 0.f, 0.f, 0.f};

    for (int k0 = 0; k0 < NK0; k0++){
        bf16x8 a[MF];
#pragma unroll
        for (int mf = 0; mf < MF; mf++)
            a[mf] = *(const bf16x8*)&wbf[(size_t)(mf * 16 + col) * K_PAD + k0 * 32 + grp * 8];
        int cell = k0 * 4 + grp;        // k8/8; CI granule index == cell (CP8=1)
        if (cell >= 25) cell = 0;
        int kh = cell / 5, kw = cell % 5;
#pragma unroll
        for (int i2 = 0; i2 < NPW; i2++){
            int ih = ihb[i2] + kh;
            int off = ((ih * 2 + (kw & 1)) * TIW_H + (iwb[i2] >> 1) + (kw >> 1)) * 8;
            bf16x8 b = *(const bf16x8*)&lds[off];
#pragma unroll
            for (int mf = 0; mf < MF; mf++)
                acc[mf][i2] = __builtin_amdgcn_mfma_f32_16x16x32_bf16(a[mf], b, acc[mf][i2], 0, 0, 0);
        }
    }

#pragma unroll
    for (int i2 = 0; i2 < NPW; i2++){
        int nsp = (wv + i2 * 4) * 16 + col;
        int oh = oh0 + nsp / 40, ow = ow0 + nsp % 40;
        size_t obase = (((size_t)n * 48 + oh) * 80 + ow) * 24;
#pragma unroll
        for (int mf = 0; mf < MF; mf++){
            int cobase = mf * 16 + grp * 4;
#pragma unroll
            for (int r = 0; r < 4; r++){
                int co = cobase + r;
                if (co < 24)
                    out[obase + co] = f2bf(fmaxf(acc[mf][i2][r] + bias[co], 0.f));
            }
        }
    }
}

// ---------------- implicit-GEMM MFMA conv (channels-last bf16 in/out), layers 2-5 ----------
template<int CI_PAD, int M_PAD, int COUT, int CO_STORE, int KHW, int CELLS_PAD,
         int S, int P, int HIN, int WIN, int HOUT, int WOUT, int TOH, int TOW>
__global__ __launch_bounds__(256) void conv_mfma(
    const u16* __restrict__ in, const u16* __restrict__ wbf,
    const float* __restrict__ bias, u16* __restrict__ out)
{
    constexpr int K_PAD = CELLS_PAD * CI_PAD;
    constexpr int CP8   = CI_PAD / 8;
    constexpr int TIH   = (TOH - 1) * S + KHW;
    constexpr int TIW   = (TOW - 1) * S + KHW;
    constexpr int TIW_H = (TIW + 1) / 2;
    constexpr int NF    = TOH * TOW / 16;
    constexpr int NK0   = K_PAD / 32;
    constexpr int MF    = M_PAD / 16;
    constexpr int NPW   = (NF + 3) / 4;
    constexpr int LDSE  = (S == 2) ? TIH * CP8 * 2 * TIW_H * 8 : TIH * CP8 * TIW * 8;
    static_assert((TOH * TOW) % 16 == 0, "N tile");
    static_assert(K_PAD % 32 == 0, "K pad");

    __shared__ u16 lds[LDSE];

    int tile = blockIdx.x, n = blockIdx.y;
    constexpr int TW_T = WOUT / TOW;
    int th = tile / TW_T, tw = tile % TW_T;
    int oh0 = th * TOH, ow0 = tw * TOW;
    int ih0 = oh0 * S - P, iw0 = ow0 * S - P;
    int tid = threadIdx.x;

    constexpr int CHUNKS = TIH * TIW * CP8;
    for (int i = tid; i < CHUNKS; i += 256){
        int c8 = i % CP8; int r2 = i / CP8;
        int iw = r2 % TIW, ih = r2 / TIW;
        int ihg = ih0 + ih, iwg = iw0 + iw;
        bf16x8 v = {0,0,0,0,0,0,0,0};
        if (ihg >= 0 && ihg < HIN && iwg >= 0 && iwg < WIN)
            v = *(const bf16x8*)&in[(((size_t)n * HIN + ihg) * WIN + iwg) * CI_PAD + c8 * 8];
        int off;
        if (S == 2) off = (((ih * CP8 + c8) * 2 + (iw & 1)) * TIW_H + (iw >> 1)) * 8;
        else        off = ((ih * CP8 + c8) * TIW + iw) * 8;
        *(bf16x8*)&lds[off] = v;
    }
    __syncthreads();

    int lane = tid & 63, wv = tid >> 6;
    int col = lane & 15, grp = lane >> 4;

    int ihb[NPW], iwb[NPW];
    bool act[NPW];
#pragma unroll
    for (int i2 = 0; i2 < NPW; i2++){
        int nf = wv + i2 * 4;
        act[i2] = (nf < NF);
        int nfc = act[i2] ? nf : 0;
        int nsp = nfc * 16 + col;
        ihb[i2] = (nsp / TOW) * S;
        iwb[i2] = (nsp % TOW) * S;
    }

    f32x4 acc[MF][NPW];
#pragma unroll
    for (int mf = 0; mf < MF; mf++)
#pragma unroll
        for (int i2 = 0; i2 < NPW; i2++)
            acc[mf][i2] = (f32x4){0.f, 0.f, 0.f, 0.f};

    for (int k0 = 0; k0 < NK0; k0++){
        bf16x8 a[MF];
#pragma unroll
        for (int mf = 0; mf < MF; mf++)
            a[mf] = *(const bf16x8*)&wbf[(size_t)(mf * 16 + col) * K_PAD + k0 * 32 + grp * 8];
        int k8 = k0 * 32 + grp * 8;
        int cell = k8 / CI_PAD;
        int ci0  = k8 - cell * CI_PAD;
        if (cell >= KHW * KHW) cell = 0;
        int kh = cell / KHW, kw = cell - (cell / KHW) * KHW;
        int cb = ci0 >> 3;
#pragma unroll
        for (int i2 = 0; i2 < NPW; i2++){
            if (!act[i2]) continue;
            int ih = ihb[i2] + kh;
            int off;
            if (S == 2) off = (((ih * CP8 + cb) * 2 + (kw & 1)) * TIW_H + (iwb[i2] >> 1) + (kw >> 1)) * 8;
            else        off = ((ih * CP8 + cb) * TIW + iwb[i2] + kw) * 8;
            bf16x8 b = *(const bf16x8*)&lds[off];
#pragma unroll
            for (int mf = 0; mf < MF; mf++)
                acc[mf][i2] = __builtin_amdgcn_mfma_f32_16x16x32_bf16(a[mf], b, acc[mf][i2], 0, 0, 0);
        }
    }

#pragma unroll
    for (int i2 = 0; i2 < NPW; i2++){
        if (!act[i2]) continue;
        int nf = wv + i2 * 4;
        int nsp = nf * 16 + col;
        int oh = oh0 + nsp / TOW, ow = ow0 + nsp % TOW;
        size_t obase = (((size_t)n * HOUT + oh) * WOUT + ow) * CO_STORE;
#pragma unroll
        for (int mf = 0; mf < MF; mf++){
            int cobase = mf * 16 + grp * 4;
#pragma unroll
            for (int r = 0; r < 4; r++){
                int co = cobase + r;
                if (co < CO_STORE){
                    float x = (co < COUT) ? fmaxf(acc[mf][i2][r] + bias[co], 0.f) : 0.f;
                    out[obase + co] = f2bf(x);
                }
            }
        }
    }
}

// ---------------- feats rearrange ----------------
__global__ __launch_bounds__(256) void extract_feats(const u16* __restrict__ a5, float* __restrict__ feats)
{
    int idx = blockIdx.x * 256 + threadIdx.x;
    if (idx >= NIMG * 12 * 20 * 64) return;
    int c = idx & 63; int t1 = idx >> 6;
    int w = t1 % 20; t1 /= 20;
    int h = t1 % 12; int n = t1 / 12;
    float v = bf2f(a5[idx]);
    int flat = w * 768 + c * 12 + h;
    int d = flat / 240, l = flat % 240;
    feats[((size_t)n * LL + l) * DD + d] = v;
}

// ---------------- proj = feats @ proj_w.T + proj_b  (64 rows per block) ----------------
__global__ __launch_bounds__(256) void proj_kernel2(
    const float* __restrict__ feats, const float* __restrict__ pw,
    const float* __restrict__ pb, float* __restrict__ proj)
{
    __shared__ float pws[64][65];
    __shared__ float fs[64][64];
    int tid = threadIdx.x;
    size_t R0 = (size_t)blockIdx.x * 64;
    for (int i = tid; i < 4096; i += 256){
        int dd = i >> 6, d = i & 63;
        pws[d][dd] = pw[dd * 64 + d];
    }
    for (int i = tid; i < 4096; i += 256){
        int r = i >> 6, d = i & 63;
        fs[r][d] = feats[(R0 + r) * 64 + d];
    }
    __syncthreads();
    for (int i = tid; i < 4096; i += 256){
        int r = i >> 6, dd = i & 63;
        float a = pb[dd];
#pragma unroll
        for (int d = 0; d < 64; d++) a = fmaf(fs[r][d], pws[d][dd], a);
        proj[(R0 + r) * 64 + dd] = a;
    }
}

// ---------------- prep: whh permute, bias combine, w_w transpose, MLP L1 transposes --------
__global__ __launch_bounds__(256) void prep(
    const float* __restrict__ w_w, const float* __restrict__ whh,
    const float* __restrict__ bih, const float* __restrict__ bhh,
    const float* __restrict__ sw1, const float* __restrict__ vw1,
    float* __restrict__ w_wT, u16* __restrict__ whh_p, float* __restrict__ bsum,
    float* __restrict__ sw1T, float* __restrict__ vw1T)
{
    int idx = blockIdx.x * 256 + threadIdx.x;
    int stride = gridDim.x * 256;
    for (int i = idx; i < 512*64; i += stride){
        int k = i / 64, dd = i % 64;
        w_wT[i] = w_w[dd*512 + k];
    }
    for (int i = idx; i < 512*2048; i += stride){
        int k = i / 2048, jj = i % 2048;
        int u = jj >> 2, g = jj & 3, j = g*512 + u;
        whh_p[i] = f2bf(whh[(size_t)j*512 + k]);
    }
    for (int i = idx; i < 2048; i += stride){
        int u = i >> 2, g = i & 3, j = g*512 + u;
        bsum[i] = bih[j] + bhh[j];
    }
    for (int i = idx; i < 512*100; i += stride){
        int k = i / 100, u = i % 100;
        sw1T[i] = sw1[u*512 + k];
        vw1T[i] = vw1[u*512 + k];
    }
}

// ---------------- gcompute via MFMA; G2 slice-contiguous layout ----------------
__global__ __launch_bounds__(256, 2) void gcompute_mfma2(
    const float* __restrict__ feats, const float* __restrict__ wih, u16* __restrict__ G)
{
    __shared__ u16 Bsw[256 * 64];
    __shared__ u16 Asw[128 * 64];
    float (*obuf)[1024] = (float(*)[1024])Asw;

    int jt = blockIdx.x, l = blockIdx.y;
    int j0 = jt * 256;
    int tid = threadIdx.x;
    int g8 = tid & 7;

    for (int p = 0; p < 8; p++){
        int row = p * 32 + (tid >> 3);
        int jj = j0 + row;
        int j = (jj & 3) * 512 + (jj >> 2);
        const float* src = wih + (size_t)j * 15360 + l * 64 + g8 * 8;
        float4 v0 = *(const float4*)src;
        float4 v1 = *(const float4*)(src + 4);
        bf16x8 pk;
        pk[0]=(short)f2bf(v0.x); pk[1]=(short)f2bf(v0.y); pk[2]=(short)f2bf(v0.z); pk[3]=(short)f2bf(v0.w);
        pk[4]=(short)f2bf(v1.x); pk[5]=(short)f2bf(v1.y); pk[6]=(short)f2bf(v1.z); pk[7]=(short)f2bf(v1.w);
        *(bf16x8*)&Bsw[(row * 8 + (g8 ^ (row & 7))) * 8] = pk;
    }
    __syncthreads();

    int lane = tid & 63, w = tid >> 6;
    int col = lane & 15, grp = lane >> 4;

    bf16x8 bfr[2][4];
#pragma unroll
    for (int k0 = 0; k0 < 2; k0++)
#pragma unroll
        for (int nf = 0; nf < 4; nf++){
            int row = w * 64 + nf * 16 + col;
            bfr[k0][nf] = *(const bf16x8*)&Bsw[(row * 8 + ((k0 * 4 + grp) ^ (row & 7))) * 8];
        }

    for (int mt = 0; mt < 3; mt++){
        int m0 = mt * 128;
        __syncthreads();
        for (int p = 0; p < 4; p++){
            int row = p * 32 + (tid >> 3);
            const float* src = feats + ((size_t)(m0 + row) * LL + l) * DD + g8 * 8;
            float4 v0 = *(const float4*)src;
            float4 v1 = *(const float4*)(src + 4);
            bf16x8 pk;
            pk[0]=(short)f2bf(v0.x); pk[1]=(short)f2bf(v0.y); pk[2]=(short)f2bf(v0.z); pk[3]=(short)f2bf(v0.w);
            pk[4]=(short)f2bf(v1.x); pk[5]=(short)f2bf(v1.y); pk[6]=(short)f2bf(v1.z); pk[7]=(short)f2bf(v1.w);
            *(bf16x8*)&Asw[(row * 8 + (g8 ^ (row & 7))) * 8] = pk;
        }
        __syncthreads();

        f32x4 acc[8][4];
#pragma unroll
        for (int mf = 0; mf < 8; mf++)
#pragma unroll
            for (int nf = 0; nf < 4; nf++) acc[mf][nf] = (f32x4){0.f,0.f,0.f,0.f};

#pragma unroll
        for (int k0 = 0; k0 < 2; k0++){
#pragma unroll
            for (int mf = 0; mf < 8; mf++){
                int row = mf * 16 + col;
                bf16x8 a = *(const bf16x8*)&Asw[(row * 8 + ((k0 * 4 + grp) ^ (row & 7))) * 8];
#pragma unroll
                for (int nf = 0; nf < 4; nf++)
                    acc[mf][nf] = __builtin_amdgcn_mfma_f32_16x16x32_bf16(a, bfr[k0][nf], acc[mf][nf], 0, 0, 0);
            }
        }
        __syncthreads();

#pragma unroll
        for (int mf = 0; mf < 8; mf++){
#pragma unroll
            for (int nf = 0; nf < 4; nf++)
#pragma unroll
                for (int r = 0; r < 4; r++)
                    obuf[w][(grp * 4 + r) * 64 + nf * 16 + col] = acc[mf][nf][r];
#pragma unroll
            for (int p = 0; p < 2; p++){
                int rloc = p * 8 + (lane >> 3);
                int c0 = (lane & 7) * 8;
                float4 r0 = *(const float4*)&obuf[w][rloc * 64 + c0];
                float4 r1 = *(const float4*)&obuf[w][rloc * 64 + c0 + 4];
                int m = m0 + mf * 16 + rloc;
                if (m < NIMG){
                    int b = m / NT, tt = m % NT;
                    int jj8 = j0 + w * 64 + c0;
                    int gg2 = jj8 >> 7, jjl = jj8 & 127;
                    bf16x8 pk;
                    pk[0]=(short)f2bf(r0.x); pk[1]=(short)f2bf(r0.y); pk[2]=(short)f2bf(r0.z); pk[3]=(short)f2bf(r0.w);
                    pk[4]=(short)f2bf(r1.x); pk[5]=(short)f2bf(r1.y); pk[6]=(short)f2bf(r1.z); pk[7]=(short)f2bf(r1.w);
                    *(bf16x8*)&G[(((size_t)(b * GPB + gg2) * NT + tt) * LL + l) * 128 + jjl] = pk;
                }
            }
        }
    }
}

// ---------------- persistent batch-partitioned scan (4 x [1 attn + 16 gates]) ----------------
// alpha handoff is SENTINEL-SIGNED: epoch e=t+1 stores (e odd ? -alpha : +alpha); gates'
// 240 threads poll the sign directly (no separate rdy flag => one less L3 round trip).
// h handoff keeps the flag line. whh term computed before alpha arrives (off critical path).
__global__ __launch_bounds__(256) void scan_pc(
    const u16* __restrict__ G, const u16* __restrict__ whh_p,
    const float* __restrict__ bsum, const float* __restrict__ proj,
    const float* __restrict__ w_wT, const float* __restrict__ w_b,
    const float* __restrict__ waw, const float* __restrict__ wab,
    float* __restrict__ alpha_g, float* __restrict__ hx_g,
    unsigned int* __restrict__ flg, float* __restrict__ hseq)
{
    int tid = threadIdx.x, blk = blockIdx.x;

    if (blk < NB){
        // ================= ATTN BLOCK (batch b) =================
        __shared__ float projT[DD * 241];
        __shared__ float hloc[HID];
        __shared__ float apjs[DD];
        __shared__ float scr[256];
        int b = blk;
        float wb0 = wab[0];

        {
            const float* src = proj + ((size_t)(b * NT + 0)) * LL * DD;
            for (int it = 0; it < 15; it++){
                int i4 = it * 256 + tid;
                int l = i4 >> 4, d0 = (i4 & 15) * 4;
                float4 v = *(const float4*)&src[l * 64 + d0];
                projT[(d0 + 0) * 241 + l] = v.x;
                projT[(d0 + 1) * 241 + l] = v.y;
                projT[(d0 + 2) * 241 + l] = v.z;
                projT[(d0 + 3) * 241 + l] = v.w;
            }
        }
        if (tid < DD) apjs[tid] = w_b[tid];
        __syncthreads();
        if (tid < LL){
            float e = 0.f;
#pragma unroll
            for (int d = 0; d < DD; d++)
                e = fmaf(tanh_f(projT[d * 241 + tid] + apjs[d]), waw[d], e);
            scr[tid] = e + wb0;
        }
        __syncthreads();
        if (tid < 64){
            float m = -1e30f;
            for (int l = tid; l < LL; l += 64) m = fmaxf(m, scr[l]);
#pragma unroll
            for (int off = 32; off; off >>= 1) m = fmaxf(m, __shfl_xor(m, off));
            float ex[4]; int c = 0; float ssum = 0.f;
            for (int l = tid; l < LL; l += 64){ float e2 = __expf(scr[l] - m); ex[c++] = e2; ssum += e2; }
#pragma unroll
            for (int off = 32; off; off >>= 1) ssum += __shfl_xor(ssum, off);
            float inv = -1.f / ssum;   // epoch 1 (odd): negative sentinel
            c = 0;
            for (int l = tid; l < LL; l += 64) ast(&alpha_g[b * LL + l], ex[c++] * inv);
        }
        __syncthreads();

        for (int t = 0; t < NT - 1; t++){
            // waves 1-3 stage proj(t+1) transposed; wave 0 polls the 16 h-flags
            if (tid >= 64){
                int idx = tid - 64;
                const float* src = proj + ((size_t)(b * NT + t + 1)) * LL * DD;
#pragma unroll
                for (int it = 0; it < 20; it++){
                    int i4 = it * 192 + idx;
                    int l = i4 >> 4, d0 = (i4 & 15) * 4;
                    float4 v = *(const float4*)&src[l * 64 + d0];
                    projT[(d0 + 0) * 241 + l] = v.x;
                    projT[(d0 + 1) * 241 + l] = v.y;
                    projT[(d0 + 2) * 241 + l] = v.z;
                    projT[(d0 + 3) * 241 + l] = v.w;
                }
            } else if (tid < GPB){
                int g = 0;
                while (aldu(&flg[b * 32 + tid]) < (unsigned int)(t + 1)){
                    if (++g > (1 << 24)) break;
                    __builtin_amdgcn_s_sleep(1);
                }
            }
            __syncthreads();

            {
                const float* hsrc = hx_g + (size_t)((t + 1) & 1) * (NB * HID) + b * HID;
                hloc[tid] = ald(&hsrc[tid]);
                hloc[tid + 256] = ald(&hsrc[tid + 256]);
            }
            __syncthreads();

            {
                int dd = tid & 63, dq = tid >> 6;
                float p = 0.f;
                for (int ki = 0; ki < 128; ki++){
                    int k = dq * 128 + ki;
                    p = fmaf(hloc[k], w_wT[k * 64 + dd], p);
                }
                scr[dq * 64 + dd] = p;
            }
            __syncthreads();
            if (tid < 64) apjs[tid] = w_b[tid] + scr[tid] + scr[64 + tid] + scr[128 + tid] + scr[192 + tid];
            __syncthreads();
            float ev = 0.f;
            if (tid < LL){
#pragma unroll
                for (int d = 0; d < DD; d++)
                    ev = fmaf(tanh_f(projT[d * 241 + tid] + apjs[d]), waw[d], ev);
                ev += wb0;
            }
            __syncthreads();
            if (tid < LL) scr[tid] = ev;
            __syncthreads();
            if (tid < 64){
                float m = -1e30f;
                for (int l = tid; l < LL; l += 64) m = fmaxf(m, scr[l]);
#pragma unroll
                for (int off = 32; off; off >>= 1) m = fmaxf(m, __shfl_xor(m, off));
                float ex[4]; int c = 0; float ssum = 0.f;
                for (int l = tid; l < LL; l += 64){ float e2 = __expf(scr[l] - m); ex[c++] = e2; ssum += e2; }
#pragma unroll
                for (int off = 32; off; off >>= 1) ssum += __shfl_xor(ssum, off);
                float sgn = ((t + 2) & 1) ? -1.f : 1.f;   // epoch t+2 sentinel sign
                float inv = sgn / ssum; c = 0;
                for (int l = tid; l < LL; l += 64) ast(&alpha_g[b * LL + l], ex[c++] * inv);
            }
            __syncthreads();
        }
    } else {
        // ================= GATES BLOCK (batch b, group g) =================
        __shared__ float als[LL];
        __shared__ float hxs[HID];
        __shared__ float red[8][128];
        __shared__ float gat[128];
        __shared__ float cxl[32];
        int idx = blk - NB;
        int b = idx & 3, g = idx >> 2;
        int jq = tid & 31, lg = tid >> 5;
        const size_t SLICE = (size_t)LL * 128;
        const u16* gbase0 = G + ((size_t)(b * GPB + g) * NT) * SLICE;

        if (tid < 32) cxl[tid] = 0.f;

        float sink = 0.f;
        if (tid >= 64){
            int pidx = tid - 64;
            const float4* pp = (const float4*)(gbase0);
            float s2 = 0.f;
#pragma unroll
            for (int i = 0; i < 20; i++){ float4 v = pp[i * 192 + pidx]; s2 += v.x + v.w; }
            sink = s2;
        }

        for (int t = 0; t < NT; t++){
            // ---- early: h(t-1) via flag line ----
            if (t == 0){
                hxs[tid] = 0.f; hxs[tid + 256] = 0.f;
                __syncthreads();
            } else {
                if (tid < GPB){
                    int gu = 0;
                    while (aldu(&flg[b * 32 + tid]) < (unsigned int)t){
                        if (++gu > (1 << 24)) break;
                        __builtin_amdgcn_s_sleep(1);
                    }
                }
                __syncthreads();
                const float* hsrc = hx_g + (size_t)(t & 1) * (NB * HID) + b * HID;
                hxs[tid] = ald(&hsrc[tid]);
                hxs[tid + 256] = ald(&hsrc[tid + 256]);
                __syncthreads();
            }
            asm volatile("" :: "v"(sink));   // consume previous G prefetch

            // ---- whh term (overlaps attn's alpha computation) ----
            float ac0 = 0.f, ac1 = 0.f, ac2 = 0.f, ac3 = 0.f;
            {
                const u16* wp = whh_p + (size_t)(lg * 64) * NJ + g * 128 + jq * 4;
#pragma unroll 8
                for (int ki = 0; ki < 64; ki++){
                    short4 wv = *(const short4*)(wp + (size_t)ki * NJ);
                    float h = hxs[lg * 64 + ki];
                    ac0 = fmaf(h, bf2f((u16)wv.x), ac0);
                    ac1 = fmaf(h, bf2f((u16)wv.y), ac1);
                    ac2 = fmaf(h, bf2f((u16)wv.z), ac2);
                    ac3 = fmaf(h, bf2f((u16)wv.w), ac3);
                }
            }

            // ---- alpha(t): sentinel-sign poll (epoch t+1) ----
            {
                unsigned int esign = (unsigned int)((t + 1) & 1);
                if (tid < LL){
                    float v = 0.f;
                    int gu = 0;
                    for (;;){
                        v = ald(&alpha_g[b * LL + tid]);
                        if ((f2u(v) >> 31) == esign) break;
                        if (++gu > (1 << 24)) break;
                        __builtin_amdgcn_s_sleep(1);
                    }
                    als[tid] = fabsf(v);
                }
                __syncthreads();
            }

            // ---- G-sum (30 l, L2-hot contiguous) ----
            {
                const u16* gp = gbase0 + (size_t)t * SLICE + (size_t)(lg * 30) * 128 + jq * 4;
#pragma unroll 6
                for (int i = 0; i < 30; i++){
                    short4 gv = *(const short4*)(gp + i * 128);
                    float al = als[lg * 30 + i];
                    ac0 = fmaf(al, bf2f((u16)gv.x), ac0);
                    ac1 = fmaf(al, bf2f((u16)gv.y), ac1);
                    ac2 = fmaf(al, bf2f((u16)gv.z), ac2);
                    ac3 = fmaf(al, bf2f((u16)gv.w), ac3);
                }
            }
            red[lg][jq * 4 + 0] = ac0;
            red[lg][jq * 4 + 1] = ac1;
            red[lg][jq * 4 + 2] = ac2;
            red[lg][jq * 4 + 3] = ac3;
            __syncthreads();
            if (tid < 128){
                float v = 0.f;
#pragma unroll
                for (int q = 0; q < 8; q++) v += red[q][tid];
                gat[tid] = v;
            }
            __syncthreads();

            // ---- local pointwise cell for units [g*32, g*32+32) ----
            if (tid < 32){
                int jjb = g * 128 + tid * 4;
                float4 bs = *(const float4*)&bsum[jjb];
                float gi = gat[tid*4 + 0] + bs.x;
                float gf = gat[tid*4 + 1] + bs.y;
                float gg = gat[tid*4 + 2] + bs.z;
                float go = gat[tid*4 + 3] + bs.w;
                float c = sigm(gf) * cxl[tid] + sigm(gi) * tanhf(gg);
                cxl[tid] = c;
                float h = sigm(go) * tanhf(c);
                int u = g * 32 + tid;
                ast(&hx_g[(size_t)((t + 1) & 1) * (NB * HID) + b * HID + u], h);
                hseq[((size_t)t * NB + b) * HID + u] = h;
            }
            __syncthreads();
            if (tid == 0) astu(&flg[b * 32 + g], (unsigned int)(t + 1));

            // prefetch G(t+1) on waves 1-3 ONLY; no immediate consume
            if (t < NT - 1 && tid >= 64){
                int pidx = tid - 64;
                const float4* pp = (const float4*)(gbase0 + (size_t)(t + 1) * SLICE);
                float s2 = 0.f;
#pragma unroll
                for (int i = 0; i < 20; i++){ float4 v = pp[i * 192 + pidx]; s2 += v.x + v.w; }
                sink = s2;
            }
        }
    }
}

// ---------------- MLP heads ----------------
__global__ __launch_bounds__(256) void mlp_kernel(
    const float* __restrict__ hseq,
    const float* __restrict__ sw1T, const float* __restrict__ sb1,
    const float* __restrict__ sw2,  const float* __restrict__ sb2,
    const float* __restrict__ sw3,  const float* __restrict__ sb3,
    const float* __restrict__ sw4,  const float* __restrict__ sb4,
    const float* __restrict__ vw1T, const float* __restrict__ vb1,
    const float* __restrict__ vw2,  const float* __restrict__ vb2,
    const float* __restrict__ vw3,  const float* __restrict__ vb3,
    const float* __restrict__ vw4,  const float* __restrict__ vb4,
    float* __restrict__ out)
{
    __shared__ float h0[HID];
    __shared__ float h1[2][100];
    __shared__ float h2[2][52];
    __shared__ float h3[2][12];
    int tb = blockIdx.x;
    int tid = threadIdx.x;
    for (int i = tid; i < HID; i += 256) h0[i] = hseq[(size_t)tb * HID + i];
    __syncthreads();
    if (tid < 100){
        float a = sb1[tid];
        for (int k = 0; k < HID; k++) a = fmaf(h0[k], sw1T[k*100 + tid], a);
        h1[0][tid] = fmaxf(a, 0.f);
    } else if (tid >= 128 && tid < 228){
        int u = tid - 128;
        float a = vb1[u];
        for (int k = 0; k < HID; k++) a = fmaf(h0[k], vw1T[k*100 + u], a);
        h1[1][u] = fmaxf(a, 0.f);
    }
    __syncthreads();
    if (tid < 50){
        float a = sb2[tid];
        for (int k = 0; k < 100; k++) a = fmaf(h1[0][k], sw2[tid*100 + k], a);
        h2[0][tid] = fmaxf(a, 0.f);
    } else if (tid >= 128 && tid < 178){
        int u = tid - 128;
        float a = vb2[u];
        for (int k = 0; k < 100; k++) a = fmaf(h1[1][k], vw2[u*100 + k], a);
        h2[1][u] = fmaxf(a, 0.f);
    }
    __syncthreads();
    if (tid < 10){
        float a = sb3[tid];
        for (int k = 0; k < 50; k++) a = fmaf(h2[0][k], sw3[tid*50 + k], a);
        h3[0][tid] = fmaxf(a, 0.f);
    } else if (tid >= 128 && tid < 138){
        int u = tid - 128;
        float a = vb3[u];
        for (int k = 0; k < 50; k++) a = fmaf(h2[1][k], vw3[u*50 + k], a);
        h3[1][u] = fmaxf(a, 0.f);
    }
    __syncthreads();
    if (tid == 0){
        float a = sb4[0];
        for (int k = 0; k < 10; k++) a = fmaf(h3[0][k], sw4[k], a);
        out[tb] = a;
    } else if (tid == 128){
        float a = vb4[0];
        for (int k = 0; k < 10; k++) a = fmaf(h3[1][k], vw4[k], a);
        out[360 + tb] = a;
    }
}

extern "C" void kernel_launch(void* const* d_in, const int* in_sizes, int n_in,
                              void* d_out, int out_size, void* d_ws, size_t ws_size,
                              hipStream_t stream)
{
    (void)in_sizes; (void)n_in; (void)out_size;
    if (ws_size < WS_NEEDED) return;

    const float* cam   = (const float*)d_in[0];
    const float* cw1   = (const float*)d_in[1];  const float* cb1 = (const float*)d_in[2];
    const float* cw2   = (const float*)d_in[3];  const float* cb2 = (const float*)d_in[4];
    const float* cw3   = (const float*)d_in[5];  const float* cb3 = (const float*)d_in[6];
    const float* cw4   = (const float*)d_in[7];  const float* cb4 = (const float*)d_in[8];
    const float* cw5   = (const float*)d_in[9];  const float* cb5 = (const float*)d_in[10];
    const float* pw    = (const float*)d_in[11]; const float* pb  = (const float*)d_in[12];
    const float* w_w   = (const float*)d_in[13]; const float* w_b = (const float*)d_in[14];
    const float* waw   = (const float*)d_in[15]; const float* wab = (const float*)d_in[16];
    const float* wih   = (const float*)d_in[17]; const float* whh = (const float*)d_in[18];
    const float* bih   = (const float*)d_in[19]; const float* bhh = (const float*)d_in[20];
    const float* sw1   = (const float*)d_in[21]; const float* sb1 = (const float*)d_in[22];
    const float* sw2   = (const float*)d_in[23]; const float* sb2 = (const float*)d_in[24];
    const float* sw3   = (const float*)d_in[25]; const float* sb3 = (const float*)d_in[26];
    const float* sw4   = (const float*)d_in[27]; const float* sb4 = (const float*)d_in[28];
    const float* vw1   = (const float*)d_in[29]; const float* vb1 = (const float*)d_in[30];
    const float* vw2   = (const float*)d_in[31]; const float* vb2 = (const float*)d_in[32];
    const float* vw3   = (const float*)d_in[33]; const float* vb3 = (const float*)d_in[34];
    const float* vw4   = (const float*)d_in[35]; const float* vb4 = (const float*)d_in[36];

    char* ws = (char*)d_ws;
    u16*   a1    = (u16*)(ws + A1_OFF);
    u16*   a2    = (u16*)(ws + A2_OFF);
    u16*   a3    = (u16*)(ws + A3_OFF);
    u16*   a4    = (u16*)(ws + A4_OFF);
    u16*   a5    = (u16*)(ws + A5_OFF);
    u16*   w1b   = (u16*)(ws + W1B_OFF);
    u16*   w2b   = (u16*)(ws + W2B_OFF);
    u16*   w3b   = (u16*)(ws + W3B_OFF);
    u16*   w4b   = (u16*)(ws + W4B_OFF);
    u16*   w5b   = (u16*)(ws + W5B_OFF);
    float* feats = (float*)(ws + FEATS_OFF);
    float* proj  = (float*)(ws + PROJ_OFF);
    float* w_wT  = (float*)(ws + WWT_OFF);
    u16*   whh_p = (u16*)  (ws + WHHP_OFF);
    float* bsum  = (float*)(ws + BSUM_OFF);
    float* sw1T  = (float*)(ws + SW1T_OFF);
    float* vw1T  = (float*)(ws + VW1T_OFF);
    float* alpha = (float*)(ws + SC_ALPHA);
    float* hx_g  = (float*)(ws + SC_HX);
    unsigned int* flg = (unsigned int*)(ws + SC_FLG);
    float* hseq  = (float*)(ws + HSEQ_OFF);
    u16*   G     = (u16*)  (ws + G_OFF);

    prep_wbf<<<64, 256, 0, stream>>>(cw1, w1b, 24,  3,  8, 5, 28, 32);
    prep_wbf<<<64, 256, 0, stream>>>(cw2, w2b, 36, 24, 24, 5, 28, 48);
    prep_wbf<<<64, 256, 0, stream>>>(cw3, w3b, 48, 36, 40, 5, 28, 48);
    prep_wbf<<<64, 256, 0, stream>>>(cw4, w4b, 64, 48, 48, 3, 10, 64);
    prep_wbf<<<64, 256, 0, stream>>>(cw5, w5b, 64, 64, 64, 3,  9, 64);

    conv1_mfma<<<dim3(12, NIMG), 256, 0, stream>>>(cam, w1b, cb1, a1);
    conv_mfma<  24,    48,   36,  40,   5,  28,   2, 2, 48,  80, 24, 40,  8, 20>
        <<<dim3(6, NIMG), 256, 0, stream>>>(a1, w2b, cb2, a2);
    conv_mfma<  40,    48,   48,  48,   5,  28,   2, 2, 24,  40, 12, 20, 12, 20>
        <<<dim3(1, NIMG), 256, 0, stream>>>(a2, w3b, cb3, a3);
    conv_mfma<  48,    64,   64,  64,   3,  10,   1, 1, 12,  20, 12, 20, 12, 20>
        <<<dim3(1, NIMG), 256, 0, stream>>>(a3, w4b, cb4, a4);
    conv_mfma<  64,    64,   64,  64,   3,   9,   1, 1, 12,  20, 12, 20, 12, 20>
        <<<dim3(1, NIMG), 256, 0, stream>>>(a4, w5b, cb5, a5);

    extract_feats<<<(NIMG*12*20*64 + 255)/256, 256, 0, stream>>>(a5, feats);
    proj_kernel2<<<NIMG*LL/64, 256, 0, stream>>>(feats, pw, pb, proj);
    prep<<<1024, 256, 0, stream>>>(w_w, whh, bih, bhh, sw1, vw1, w_wT, whh_p, bsum, sw1T, vw1T);
    gcompute_mfma2<<<dim3(8, 240), 256, 0, stream>>>(feats, wih, G);

    // zero scan state: alpha(4KB) + hx parity buffers(16KB) + flags(512B)
    hipMemsetAsync(ws + SC_ALPHA, 0, 20992, stream);

    scan_pc<<<TBLK, 256, 0, stream>>>(G, whh_p, bsum, proj, w_wT, w_b, waw, wab,
                                      alpha, hx_g, flg, hseq);

    mlp_kernel<<<360, 256, 0, stream>>>(hseq,
        sw1T, sb1, sw2, sb2, sw3, sb3, sw4, sb4,
        vw1T, vb1, vw2, vb2, vw3, vb3, vw4, vb4, (float*)d_out);
}